// Round 9
// baseline (1037.679 us; speedup 1.0000x reference)
//
#include <hip/hip_runtime.h>

#define NSTEPS 10

typedef __attribute__((ext_vector_type(8))) short bf16x8;
typedef __attribute__((ext_vector_type(4))) float f32x4;

__device__ __forceinline__ float sigmoidf_(float x) { return 1.0f / (1.0f + __expf(-x)); }
__device__ __forceinline__ float tanh_fast(float x) {
  const float e = __expf(2.f * x);
  return 1.f - 2.f / (e + 1.f);
}
__device__ __forceinline__ short bf16_(float x) {   // RNE, pack phase
  union { float f; unsigned u; } c; c.f = x;
  unsigned r = (c.u + 0x7FFFu + ((c.u >> 16) & 1u)) >> 16;
  return (short)r;
}
__device__ __forceinline__ unsigned pk2_(float a, float b) {  // [lo:a|hi:b]
  union { float f; unsigned u; } ca, cb; ca.f = a; cb.f = b;
  return __builtin_amdgcn_perm(cb.u + 0x8000u, ca.u + 0x8000u, 0x07060302u);
}
__device__ __forceinline__ short pk1_(float a) {
  union { float f; unsigned u; } c; c.f = a;
  return (short)((c.u + 0x8000u) >> 16);
}
__device__ __forceinline__ float lo_(unsigned u) { union { unsigned u; float f; } c; c.u = u << 16; return c.f; }
__device__ __forceinline__ float hi_(unsigned u) { union { unsigned u; float f; } c; c.u = u & 0xffff0000u; return c.f; }

__device__ __forceinline__ f32x4 mfma_16x16x32(bf16x8 a, bf16x8 b, f32x4 c) {
  return __builtin_amdgcn_mfma_f32_16x16x32_bf16(a, b, c, 0, 0, 0);
}

// chunk table (1 chunk = 512 bf16)
#define C_W2A   0
#define C_W2B   32
#define C_W3A   64
#define C_W3B   68
#define C_ACOMB 72     // [m1w1 src (16)] + [m2w1 dst (16)]
#define C_W1AD  104
#define C_W1BS  120
#define C_RO1   136
#define C_RO2   152
#define C_Q     184
#define C_G1    189
#define C_G2    237
#define TOTAL_CHUNKS 285

struct PackJob { const float* src; int N; int KS; int nchunks; };
struct PackArgs {
  PackJob jb[10];
  const float* Qw; const float* Qb;
  const float* g1wih; const float* g1whh;
  const float* g2wih; const float* g2whh;
};

__device__ __forceinline__ float pack_val(const PackArgs& a, int g) {
  int c = g >> 9;
  const int r = g & 511;
  const int j = r & 7, n = (r >> 3) & 15, q = (r >> 7) & 3;
  const int kq = q * 8 + j;
  float val = 0.f;
  bool done = false;
  #pragma unroll
  for (int ji = 0; ji < 10; ++ji) {
    if (!done && c < a.jb[ji].nchunks) {
      const int ks = c % a.jb[ji].KS;
      const int nt = c / a.jb[ji].KS;
      const int k = ks * 32 + kq;
      val = a.jb[ji].src[(size_t)k * a.jb[ji].N + nt * 16 + n];
      done = true;
    }
    if (!done) c -= a.jb[ji].nchunks;
  }
  if (!done) {
    if (c < 5) {  // q-transform (K padded 16->32)
      val = 0.f;
      if (kq < 16) val = (c < 4) ? a.Qw[c * 256 + n * 16 + kq] : a.Qb[n * 16 + kq];
    } else {      // GRU: 256 cols = [r|z|in|hn], K=96; s-remap: s = (nq&15)*4 + (nq>>4)
      c -= 5;
      const float* wih = (c < 48) ? a.g1wih : a.g2wih;
      const float* whh = (c < 48) ? a.g1whh : a.g2whh;
      if (c >= 48) c -= 48;
      const int nt = c / 3, ks = c % 3;
      const int k = ks * 32 + kq;
      const int ng = nt * 16 + n;
      const int gate = ng >> 6;
      const int nq = ng & 63;
      const int s = (nq & 15) * 4 + (nq >> 4);
      val = 0.f;
      if (gate == 0) {
        if (k < 16) val = wih[k * 192 + s];
        else if (k < 80) val = whh[(k - 16) * 192 + s];
      } else if (gate == 1) {
        if (k < 16) val = wih[k * 192 + 64 + s];
        else if (k < 80) val = whh[(k - 16) * 192 + 64 + s];
      } else if (gate == 2) {
        if (k < 16) val = wih[k * 192 + 128 + s];
      } else {
        if (k >= 16 && k < 80) val = whh[(k - 16) * 192 + 128 + s];
      }
    }
  }
  return val;
}

__global__ __launch_bounds__(256) void k_pack(PackArgs a, short* __restrict__ out, int total) {
  const int g = blockIdx.x * 256 + threadIdx.x;
  if (g < total) out[g] = bf16_(pack_val(a, g));
}

// ---------------------------------------------------------------------------
// var GRU tile (s-remapped): lane owns cols sb=m*4..+3; vector epilogue.
// ---------------------------------------------------------------------------
__device__ __forceinline__ void var_gru_tile(
    const short* wb, const float* gbih, const float* gbhh,
    const short* SA, float* gruH, short* outTile, int outStr,
    int rbase, int Nn, int lane, int wave, int m, int quad, bool writeH)
{
  f32x4 acc[16] = {};
  #pragma unroll
  for (int ks = 0; ks < 3; ++ks) {
    const bf16x8 av = *(const bf16x8*)&SA[(wave * 16 + m) * 104 + ks * 32 + quad * 8];
    #pragma unroll
    for (int nt = 0; nt < 16; ++nt)
      acc[nt] = mfma_16x16x32(av, ((const bf16x8*)(wb + C_G2 * 512))[(nt * 3 + ks) * 64 + lane], acc[nt]);
  }
  const int sb = m * 4;
  const f32x4 bir = *(const f32x4*)(gbih + sb);
  const f32x4 bhr = *(const f32x4*)(gbhh + sb);
  const f32x4 biz = *(const f32x4*)(gbih + 64 + sb);
  const f32x4 bhz = *(const f32x4*)(gbhh + 64 + sb);
  const f32x4 bi4 = *(const f32x4*)(gbih + 128 + sb);
  const f32x4 bh4 = *(const f32x4*)(gbhh + 128 + sb);
  #pragma unroll
  for (int reg = 0; reg < 4; ++reg) {
    const int lr = wave * 16 + quad * 4 + reg, rg = rbase + lr;
    uint2 pv; pv.x = 0u; pv.y = 0u;
    if (rg < Nn) {
      const f32x4 ho = *(const f32x4*)(gruH + (size_t)rg * 64 + sb);
      f32x4 hn;
      #pragma unroll
      for (int nt = 0; nt < 4; ++nt) {
        const float rr = sigmoidf_(acc[nt][reg] + bir[nt] + bhr[nt]);
        const float zz = sigmoidf_(acc[4 + nt][reg] + biz[nt] + bhz[nt]);
        const float nn = tanh_fast(acc[8 + nt][reg] + bi4[nt] + rr * (acc[12 + nt][reg] + bh4[nt]));
        hn[nt] = (1.f - zz) * nn + zz * ho[nt];
      }
      if (writeH) *(f32x4*)(gruH + (size_t)rg * 64 + sb) = hn;
      pv.x = pk2_(hn[0], hn[1]);
      pv.y = pk2_(hn[2], hn[3]);
    }
    *(uint2*)&outTile[lr * outStr + sb] = pv;
  }
}

// ---------------------------------------------------------------------------
// transposed 128-col partial: Ps[fac 0..31][col 0..127] = src @ W (chunk as A).
// ---------------------------------------------------------------------------
__device__ __forceinline__ void partial_gemm_T(
    const short* chunk, const short* srcTile, int srcStr, short* Ps,
    int lane, int wave, int m, int quad)
{
  const int nt = wave & 1, mt0 = (wave >> 1) * 4;
  f32x4 acc[4] = {};
  #pragma unroll
  for (int ks = 0; ks < 2; ++ks) {
    const bf16x8 bfr = *(const bf16x8*)&srcTile[(nt * 16 + m) * srcStr + ks * 32 + quad * 8];
    #pragma unroll
    for (int j = 0; j < 4; ++j)
      acc[j] = mfma_16x16x32(((const bf16x8*)chunk)[((mt0 + j) * 2 + ks) * 64 + lane], bfr, acc[j]);
  }
  #pragma unroll
  for (int j = 0; j < 4; ++j) {
    const int col = (mt0 + j) * 16 + quad * 4;
    uint2 pv;
    pv.x = pk2_(acc[j][0], acc[j][1]);
    pv.y = pk2_(acc[j][2], acc[j][3]);
    *(uint2*)&Ps[(nt * 16 + m) * 136 + col] = pv;
  }
}

// ---------------------------------------------------------------------------
// edge MLP tail, transposed L2. Single internal barrier (protects ms/Ps
// overlay); h1/h2/ms rows are wave-private so other stage crossings rely on
// per-wave in-order DS execution. feats loaded direct from global (16B
// broadcast per quad-row).
// ---------------------------------------------------------------------------
__device__ __forceinline__ void edge_tail(
    const short* wb, int cw2, int cw3,
    const float* b2, const float* b3,
    short* h1s, short* ms, const float* feat_g, int e0, int E,
    int lane, int wave, int m, int quad, float* mq)
{
  // L2 transposed: reads + writes wave-private h1 rows
  {
    f32x4 acc[8] = {};
    #pragma unroll
    for (int ks = 0; ks < 4; ++ks) {
      const bf16x8 bfr = *(const bf16x8*)&h1s[(wave * 16 + m) * 136 + ks * 32 + quad * 8];
      #pragma unroll
      for (int mt = 0; mt < 8; ++mt)
        acc[mt] = mfma_16x16x32(((const bf16x8*)(wb + cw2))[(mt * 4 + ks) * 64 + lane], bfr, acc[mt]);
    }
    #pragma unroll
    for (int mt = 0; mt < 8; ++mt) {
      const int col = mt * 16 + quad * 4;
      const f32x4 bv = *(const f32x4*)(b2 + col);
      uint2 pv;
      pv.x = pk2_(fmaxf(acc[mt][0] + bv[0], 0.f), fmaxf(acc[mt][1] + bv[1], 0.f));
      pv.y = pk2_(fmaxf(acc[mt][2] + bv[2], 0.f), fmaxf(acc[mt][3] + bv[3], 0.f));
      *(uint2*)&h1s[(wave * 16 + m) * 136 + col] = pv;
    }
  }
  __syncthreads();   // all waves done with Ps reads (h1 staging) before ms writes

  // L3: m = h2 @ W3 (wave-private rows)
  f32x4 acc3 = {};
  #pragma unroll
  for (int ks = 0; ks < 4; ++ks) {
    const bf16x8 afr = *(const bf16x8*)&h1s[(wave * 16 + m) * 136 + ks * 32 + quad * 8];
    acc3 = mfma_16x16x32(afr, ((const bf16x8*)(wb + cw3))[ks * 64 + lane], acc3);
  }
  const float b3v = b3[m];
  #pragma unroll
  for (int rr = 0; rr < 4; ++rr) {
    const int row = wave * 16 + quad * 4 + rr;
    ms[row * 40 + m] = pk1_(acc3[rr] + b3v);
    ms[row * 40 + 16 + m] = 0;
  }
  // no barrier: ms rows wave-private, DS in-order per wave

  // q transform
  f32x4 accY[5] = {};
  {
    const bf16x8 afr = *(const bf16x8*)&ms[(wave * 16 + m) * 40 + quad * 8];
    #pragma unroll
    for (int tq = 0; tq < 5; ++tq)
      accY[tq] = mfma_16x16x32(afr, ((const bf16x8*)(wb + C_Q * 512))[tq * 64 + lane], accY[tq]);
  }
  #pragma unroll
  for (int rr = 0; rr < 4; ++rr) {
    const int row = wave * 16 + quad * 4 + rr;
    const int er = e0 + row;
    const f32x4 f = *(const f32x4*)(feat_g + (size_t)(er < E ? er : 0) * 4);
    mq[rr] = accY[4][rr] + f.x * accY[0][rr] + f.y * accY[1][rr]
                         + f.z * accY[2][rr] + f.w * accY[3][rr];
  }
}

// ---------------------------------------------------------------------------
// k_phaseA: var GRU (if msgIn) + transposed combined partials -> Abuf/Bbuf.
// ---------------------------------------------------------------------------
__global__ __launch_bounds__(256) void k_phaseA(
    const float* __restrict__ msgIn, float* __restrict__ msgZero,
    float* __restrict__ var_h,
    short* __restrict__ Abuf, short* __restrict__ Bbuf,
    const short* __restrict__ wb,
    const float* __restrict__ gbih, const float* __restrict__ gbhh, int N)
{
  __shared__ short SA[64 * 104];
  __shared__ short Xs[64 * 72];
  const int t = threadIdx.x, lane = t & 63, wave = t >> 6;
  const int m = lane & 15, quad = lane >> 4;
  const int rbase = blockIdx.x * 64;

  if (msgIn) {
    {
      const int r = t >> 2, q4 = t & 3, rg = rbase + r;
      #pragma unroll
      for (int i = 0; i < 6; ++i) {
        const int c = q4 * 4 + i * 16;
        f32x4 v = {0.f, 0.f, 0.f, 0.f};
        if (rg < N) {
          if (c < 16)      v = *(const f32x4*)(msgIn + (size_t)rg * 16 + c);
          else if (c < 80) v = *(const f32x4*)(var_h + (size_t)rg * 64 + (c - 16));
        }
        *(unsigned*)&SA[r * 104 + c]     = pk2_(v.x, v.y);
        *(unsigned*)&SA[r * 104 + c + 2] = pk2_(v.z, v.w);
      }
      if (rbase + r < N) {
        f32x4 z = {0.f, 0.f, 0.f, 0.f};
        *(f32x4*)(msgZero + (size_t)(rbase + r) * 16 + q4 * 4) = z;
      }
    }
    __syncthreads();
    var_gru_tile(wb, gbih, gbhh, SA, var_h, Xs, 72,
                 rbase, N, lane, wave, m, quad, true);
    __syncthreads();
  } else {
    const int r = t >> 2, q4 = t & 3, rg = rbase + r;
    #pragma unroll
    for (int i = 0; i < 4; ++i) {
      const int cc = q4 * 4 + i * 16;
      f32x4 v = {0.f, 0.f, 0.f, 0.f};
      if (rg < N) v = *(const f32x4*)(var_h + (size_t)rg * 64 + cc);
      *(unsigned*)&Xs[r * 72 + cc]     = pk2_(v.x, v.y);
      *(unsigned*)&Xs[r * 72 + cc + 2] = pk2_(v.z, v.w);
    }
    __syncthreads();
  }

  // transposed combined GEMM: D[col 0..255][row]; wave = row-tile
  f32x4 acc[16] = {};
  #pragma unroll
  for (int ks = 0; ks < 2; ++ks) {
    const bf16x8 bfr = *(const bf16x8*)&Xs[(wave * 16 + m) * 72 + ks * 32 + quad * 8];
    #pragma unroll
    for (int mt = 0; mt < 16; ++mt)
      acc[mt] = mfma_16x16x32(((const bf16x8*)(wb + C_ACOMB * 512))[(mt * 2 + ks) * 64 + lane], bfr, acc[mt]);
  }
  const int rg = rbase + wave * 16 + m;
  if (rg < N) {
    #pragma unroll
    for (int mt = 0; mt < 16; ++mt) {
      const int col = mt * 16 + quad * 4;
      short* dst = (col < 128) ? Abuf : Bbuf;
      uint2 pv;
      pv.x = pk2_(acc[mt][0], acc[mt][1]);
      pv.y = pk2_(acc[mt][2], acc[mt][3]);
      *(uint2*)&dst[(size_t)rg * 128 + (col & 127)] = pv;
    }
  }
}

// ---------------------------------------------------------------------------
// k_phaseB: v2f edge + factor GRU + f2v edge. 32768 B LDS -> 5 blocks/CU.
// Gathers prefetched into registers; 7 barriers (was 11).
// ---------------------------------------------------------------------------
__global__ __launch_bounds__(256, 5) void k_phaseB(
    const short* __restrict__ Abuf, const short* __restrict__ Bbuf,
    const int* __restrict__ v2f_src, const int* __restrict__ f2v_dst,
    const float* __restrict__ featA, const float* __restrict__ featB,
    const float* __restrict__ m1b1, const float* __restrict__ m1b2,
    const float* __restrict__ m1b3,
    const float* __restrict__ m2b1, const float* __restrict__ m2b2,
    const float* __restrict__ m2b3,
    const float* __restrict__ g1bih, const float* __restrict__ g1bhh,
    const short* __restrict__ wb,
    float* __restrict__ fac_h, float* __restrict__ msgV, int E, int F)
{
  __shared__ __align__(16) char smemB[32768];
  short* h1s = (short*)(smemB);            // 64*136*2 = 17408
  short* Ps  = (short*)(smemB + 17408);    // 32*136*2 = 8704  (ms overlays)
  short* ms  = (short*)(smemB + 17408);    // 64*40*2  = 5120
  short* Fs2 = (short*)(smemB);            // 32*72*2  = 4608  (overlays h1s)
  short* AsG = (short*)(smemB + 26112);    // 32*104*2 = 6656  -> 32768 total

  const int t = threadIdx.x, lane = t & 63, wave = t >> 6;
  const int m = lane & 15, quad = lane >> 4;
  const int e0 = blockIdx.x * 64, f0 = blockIdx.x * 32;
  const int r = t >> 2, q4 = t & 3;

  // ---- early: indices + pass-1 gather prefetch (registers) ----
  const bool okR = (e0 + r) < E;
  const int sidx_r = okR ? v2f_src[e0 + r] : 0;
  const int didx_r = okR ? f2v_dst[e0 + r] : 0;
  int aidx[4];
  #pragma unroll
  for (int rr = 0; rr < 4; ++rr) {
    const int er = e0 + wave * 16 + quad * 4 + rr;
    aidx[rr] = (er < E) ? f2v_dst[er] : 0;
  }
  uint4 uaP[4];
  {
    const short* paA = Abuf + (size_t)sidx_r * 128;
    #pragma unroll
    for (int i = 0; i < 4; ++i)
      uaP[i] = *(const uint4*)(paA + (q4 + i * 4) * 8);
  }

  // ---- S0: stage fac_h -> AsG [pad16|h64|pad16-zero] ----
  {
    const int hr = t >> 3, hc = (t & 7) * 8;
    const int f = f0 + hr;
    f32x4 a0 = {0.f,0.f,0.f,0.f}, a1 = {0.f,0.f,0.f,0.f};
    if (f < F) {
      a0 = *(const f32x4*)(fac_h + (size_t)f * 64 + hc);
      a1 = *(const f32x4*)(fac_h + (size_t)f * 64 + hc + 4);
    }
    uint4 o;
    o.x = pk2_(a0.x, a0.y); o.y = pk2_(a0.z, a0.w);
    o.z = pk2_(a1.x, a1.y); o.w = pk2_(a1.z, a1.w);
    *(uint4*)&AsG[hr * 104 + 16 + hc] = o;
    if (t < 64) {
      uint4 z = make_uint4(0u, 0u, 0u, 0u);
      *(uint4*)&AsG[(t >> 1) * 104 + 80 + (t & 1) * 8] = z;
    }
  }
  __syncthreads();                                                   // [1]

  // ---- S1: local v2f dst-partial ----
  partial_gemm_T(wb + C_W1AD * 512, AsG + 16, 104, Ps, lane, wave, m, quad);
  __syncthreads();                                                   // [2]

  // ---- S2: v2f h1 = relu(uaP + Ps[e>>1] + m1b1); then prefetch Bbuf ----
  {
    const short* pb = Ps + (r >> 1) * 136;
    #pragma unroll
    for (int i = 0; i < 4; ++i) {
      const int col = (q4 + i * 4) * 8;
      uint4 o = make_uint4(0u, 0u, 0u, 0u);
      if (okR) {
        const uint4 ua = uaP[i];
        const uint4 ub = *(const uint4*)(pb + col);
        const f32x4 ba = *(const f32x4*)(m1b1 + col);
        const f32x4 bb = *(const f32x4*)(m1b1 + col + 4);
        o.x = pk2_(fmaxf(lo_(ua.x) + lo_(ub.x) + ba.x, 0.f),
                   fmaxf(hi_(ua.x) + hi_(ub.x) + ba.y, 0.f));
        o.y = pk2_(fmaxf(lo_(ua.y) + lo_(ub.y) + ba.z, 0.f),
                   fmaxf(hi_(ua.y) + hi_(ub.y) + ba.w, 0.f));
        o.z = pk2_(fmaxf(lo_(ua.z) + lo_(ub.z) + bb.x, 0.f),
                   fmaxf(hi_(ua.z) + hi_(ub.z) + bb.y, 0.f));
        o.w = pk2_(fmaxf(lo_(ua.w) + lo_(ub.w) + bb.z, 0.f),
                   fmaxf(hi_(ua.w) + hi_(ub.w) + bb.w, 0.f));
      }
      *(uint4*)&h1s[r * 136 + col] = o;
    }
  }
  uint4 ubP[4];
  {
    const short* paB = Bbuf + (size_t)didx_r * 128;
    #pragma unroll
    for (int i = 0; i < 4; ++i)
      ubP[i] = *(const uint4*)(paB + (q4 + i * 4) * 8);
  }
  // no barrier: h1 rows wave-private

  // ---- S3-5: edge tail 1 (internal barrier [3]) ----
  float mq[4];
  edge_tail(wb, C_W2A * 512, C_W3A * 512, m1b2, m1b3,
            h1s, ms, featA, e0, E, lane, wave, m, quad, mq);
  {
    const int fl = wave * 8 + quad * 2;
    AsG[fl * 104 + m]       = pk1_(mq[0] + mq[1]);
    AsG[(fl + 1) * 104 + m] = pk1_(mq[2] + mq[3]);
  }
  __syncthreads();                                                   // [4]

  // ---- S6: factor GRU on 32 local rows ----
  {
    const int mtg = wave >> 1, sh = wave & 1;
    f32x4 accG[8] = {};
    #pragma unroll
    for (int ks = 0; ks < 3; ++ks) {
      const bf16x8 av = *(const bf16x8*)&AsG[(mtg * 16 + m) * 104 + ks * 32 + quad * 8];
      #pragma unroll
      for (int g = 0; g < 4; ++g)
        #pragma unroll
        for (int nt2 = 0; nt2 < 2; ++nt2) {
          const int nt = g * 4 + sh * 2 + nt2;
          accG[g * 2 + nt2] = mfma_16x16x32(
              av, ((const bf16x8*)(wb + C_G1 * 512))[(nt * 3 + ks) * 64 + lane],
              accG[g * 2 + nt2]);
        }
    }
    const int sb = m * 4 + sh * 2;
    const float br0 = g1bih[sb] + g1bhh[sb],           br1 = g1bih[sb + 1] + g1bhh[sb + 1];
    const float bz0 = g1bih[64 + sb] + g1bhh[64 + sb], bz1 = g1bih[65 + sb] + g1bhh[65 + sb];
    const float bi0 = g1bih[128 + sb], bi1 = g1bih[129 + sb];
    const float bh0 = g1bhh[128 + sb], bh1 = g1bhh[129 + sb];
    #pragma unroll
    for (int reg = 0; reg < 4; ++reg) {
      const int lr = mtg * 16 + quad * 4 + reg;
      const int f = f0 + lr;
      float hn0 = 0.f, hn1 = 0.f;
      if (f < F) {
        const float2 ho = *(const float2*)(fac_h + (size_t)f * 64 + sb);
        const float r0 = sigmoidf_(accG[0][reg] + br0);
        const float r1 = sigmoidf_(accG[1][reg] + br1);
        const float z0 = sigmoidf_(accG[2][reg] + bz0);
        const float z1 = sigmoidf_(accG[3][reg] + bz1);
        const float n0 = tanh_fast(accG[4][reg] + bi0 + r0 * (accG[6][reg] + bh0));
        const float n1 = tanh_fast(accG[5][reg] + bi1 + r1 * (accG[7][reg] + bh1));
        hn0 = (1.f - z0) * n0 + z0 * ho.x;
        hn1 = (1.f - z1) * n1 + z1 * ho.y;
        float2 hw; hw.x = hn0; hw.y = hn1;
        *(float2*)(fac_h + (size_t)f * 64 + sb) = hw;
      }
      *(unsigned*)&Fs2[lr * 72 + sb] = pk2_(hn0, hn1);
    }
  }
  __syncthreads();                                                   // [5]

  // ---- S7: local f2v src-partial ----
  partial_gemm_T(wb + C_W1BS * 512, Fs2, 72, Ps, lane, wave, m, quad);
  __syncthreads();                                                   // [6]

  // ---- S8: f2v h1 = relu(Ps[e>>1] + ubP + m2b1) ----
  {
    const short* pa = Ps + (r >> 1) * 136;
    #pragma unroll
    for (int i = 0; i < 4; ++i) {
      const int col = (q4 + i * 4) * 8;
      uint4 o = make_uint4(0u, 0u, 0u, 0u);
      if (okR) {
        const uint4 ua = *(const uint4*)(pa + col);
        const uint4 ub = ubP[i];
        const f32x4 ba = *(const f32x4*)(m2b1 + col);
        const f32x4 bb = *(const f32x4*)(m2b1 + col + 4);
        o.x = pk2_(fmaxf(lo_(ua.x) + lo_(ub.x) + ba.x, 0.f),
                   fmaxf(hi_(ua.x) + hi_(ub.x) + ba.y, 0.f));
        o.y = pk2_(fmaxf(lo_(ua.y) + lo_(ub.y) + ba.z, 0.f),
                   fmaxf(hi_(ua.y) + hi_(ub.y) + ba.w, 0.f));
        o.z = pk2_(fmaxf(lo_(ua.z) + lo_(ub.z) + bb.x, 0.f),
                   fmaxf(hi_(ua.z) + hi_(ub.z) + bb.y, 0.f));
        o.w = pk2_(fmaxf(lo_(ua.w) + lo_(ub.w) + bb.z, 0.f),
                   fmaxf(hi_(ua.w) + hi_(ub.w) + bb.w, 0.f));
      }
      *(uint4*)&h1s[r * 136 + col] = o;
    }
  }
  // no barrier: h1 rows wave-private

  // ---- S9-11: edge tail 2 (internal barrier [7]) + atomics ----
  float mq2[4];
  edge_tail(wb, C_W2B * 512, C_W3B * 512, m2b2, m2b3,
            h1s, ms, featB, e0, E, lane, wave, m, quad, mq2);
  #pragma unroll
  for (int rr = 0; rr < 4; ++rr) {
    const int erow = wave * 16 + quad * 4 + rr;
    if (e0 + erow < E)
      atomicAdd(msgV + (size_t)aidx[rr] * 16 + m, mq2[rr]);
  }
}

// ---------------------------------------------------------------------------
// k_readout_f: final var GRU + RO1 + RO2 (transposed) + RO3 + softmax.
// ---------------------------------------------------------------------------
__global__ __launch_bounds__(256) void k_readout_f(
    const float* __restrict__ gruMsg, const float* __restrict__ gruH,
    const short* __restrict__ wb,
    const float* __restrict__ gbih, const float* __restrict__ gbhh,
    const float* __restrict__ rob1, const float* __restrict__ rob2,
    const float* __restrict__ row3, const float* __restrict__ rob3,
    float* __restrict__ out, int rows)
{
  __shared__ short SA[64 * 104];
  __shared__ short SH[64 * 72];
  __shared__ short S1[64 * 136];
  __shared__ short S2[64 * 136];
  __shared__ float w3s[256];
  const int t = threadIdx.x, lane = t & 63, wave = t >> 6;
  const int m = lane & 15, quad = lane >> 4;
  const int rbase = blockIdx.x * 64;

  w3s[t] = row3[t];
  {
    const int r = t >> 2, q4 = t & 3, rg = rbase + r;
    #pragma unroll
    for (int i = 0; i < 6; ++i) {
      const int c = q4 * 4 + i * 16;
      f32x4 v = {0.f, 0.f, 0.f, 0.f};
      if (rg < rows) {
        if (c < 16)      v = *(const f32x4*)(gruMsg + (size_t)rg * 16 + c);
        else if (c < 80) v = *(const f32x4*)(gruH + (size_t)rg * 64 + (c - 16));
      }
      *(unsigned*)&SA[r * 104 + c]     = pk2_(v.x, v.y);
      *(unsigned*)&SA[r * 104 + c + 2] = pk2_(v.z, v.w);
    }
  }
  __syncthreads();
  var_gru_tile(wb, gbih, gbhh, SA, (float*)gruH, SH, 72,
               rbase, rows, lane, wave, m, quad, false);
  __syncthreads();

  // RO1 (transposed)
  {
    f32x4 acc[8] = {};
    #pragma unroll
    for (int ks = 0; ks < 2; ++ks) {
      const bf16x8 bfr = *(const bf16x8*)&SH[(wave * 16 + m) * 72 + ks * 32 + quad * 8];
      #pragma unroll
      for (int mt = 0; mt < 8; ++mt)
        acc[mt] = mfma_16x16x32(((const bf16x8*)(wb + C_RO1 * 512))[(mt * 2 + ks) * 64 + lane], bfr, acc[mt]);
    }
    #pragma unroll
    for (int mt = 0; mt < 8; ++mt) {
      const int col = mt * 16 + quad * 4;
      const f32x4 bv = *(const f32x4*)(rob1 + col);
      uint2 pv;
      pv.x = pk2_(fmaxf(acc[mt][0] + bv[0], 0.f), fmaxf(acc[mt][1] + bv[1], 0.f));
      pv.y = pk2_(fmaxf(acc[mt][2] + bv[2], 0.f), fmaxf(acc[mt][3] + bv[3], 0.f));
      *(uint2*)&S1[(wave * 16 + m) * 136 + col] = pv;
    }
  }
  __syncthreads();

  // RO2 (transposed)
  {
    f32x4 acc[8] = {};
    #pragma unroll
    for (int ks = 0; ks < 4; ++ks) {
      const bf16x8 bfr = *(const bf16x8*)&S1[(wave * 16 + m) * 136 + ks * 32 + quad * 8];
      #pragma unroll
      for (int mt = 0; mt < 8; ++mt)
        acc[mt] = mfma_16x16x32(((const bf16x8*)(wb + C_RO2 * 512))[(mt * 4 + ks) * 64 + lane], bfr, acc[mt]);
    }
    #pragma unroll
    for (int mt = 0; mt < 8; ++mt) {
      const int col = mt * 16 + quad * 4;
      const f32x4 bv = *(const f32x4*)(rob2 + col);
      uint2 pv;
      pv.x = pk2_(fmaxf(acc[mt][0] + bv[0], 0.f), fmaxf(acc[mt][1] + bv[1], 0.f));
      pv.y = pk2_(fmaxf(acc[mt][2] + bv[2], 0.f), fmaxf(acc[mt][3] + bv[3], 0.f));
      *(uint2*)&S2[(wave * 16 + m) * 136 + col] = pv;
    }
  }
  __syncthreads();

  if (t < 64) {
    const int rg = rbase + t;
    if (rg < rows) {
      float l0 = rob3[0], l1 = rob3[1];
      #pragma unroll 8
      for (int k = 0; k < 128; k += 2) {
        const unsigned u = *(const unsigned*)&S2[t * 136 + k];
        const float x0 = lo_(u), x1 = hi_(u);
        l0 = fmaf(x0, w3s[k * 2 + 0], l0);
        l1 = fmaf(x0, w3s[k * 2 + 1], l1);
        l0 = fmaf(x1, w3s[k * 2 + 2], l0);
        l1 = fmaf(x1, w3s[k * 2 + 3], l1);
      }
      const float mx = fmaxf(l0, l1);
      const float e0 = __expf(l0 - mx), e1 = __expf(l1 - mx);
      const float inv = 1.f / (e0 + e1);
      out[(size_t)rg * 2 + 0] = e0 * inv;
      out[(size_t)rg * 2 + 1] = e1 * inv;
    }
  }
}

// ---------------------------------------------------------------------------
extern "C" void kernel_launch(void* const* d_in, const int* in_sizes, int n_in,
                              void* d_out, int out_size, void* d_ws, size_t ws_size,
                              hipStream_t stream)
{
  const int*   v2f_src  = (const int*)d_in[0];
  const int*   f2v_dst  = (const int*)d_in[3];
  const float* feat_v2f = (const float*)d_in[4];
  const float* feat_f2v = (const float*)d_in[5];
  const float* Qw    = (const float*)d_in[8];
  const float* Qb    = (const float*)d_in[9];
  const float* m1w1  = (const float*)d_in[10];
  const float* m1b1  = (const float*)d_in[11];
  const float* m1w2  = (const float*)d_in[12];
  const float* m1b2  = (const float*)d_in[13];
  const float* m1w3  = (const float*)d_in[14];
  const float* m1b3  = (const float*)d_in[15];
  const float* m2w1  = (const float*)d_in[16];
  const float* m2b1  = (const float*)d_in[17];
  const float* m2w2  = (const float*)d_in[18];
  const float* m2b2  = (const float*)d_in[19];
  const float* m2w3  = (const float*)d_in[20];
  const float* m2b3  = (const float*)d_in[21];
  const float* g1wih = (const float*)d_in[22];
  const float* g1whh = (const float*)d_in[23];
  const float* g1bih = (const float*)d_in[24];
  const float* g1bhh = (const float*)d_in[25];
  const float* g2wih = (const float*)d_in[26];
  const float* g2whh = (const float*)d_in[27];
  const float* g2bih = (const float*)d_in[28];
  const float* g2bhh = (const float*)d_in[29];
  const float* row1  = (const float*)d_in[30];
  const float* rob1  = (const float*)d_in[31];
  const float* row2  = (const float*)d_in[32];
  const float* rob2  = (const float*)d_in[33];
  const float* row3  = (const float*)d_in[34];
  const float* rob3  = (const float*)d_in[35];

  const int E = in_sizes[0];
  const int N = out_size / 2;
  const int F = E / 2;

  float* wsf   = (float*)d_ws;
  float* var_h = wsf;                               // N*64
  float* fac_h = var_h + (size_t)N * 64;            // F*64
  float* msgV  = fac_h + (size_t)F * 64;            // N*16
  short* Abuf  = (short*)(msgV + (size_t)N * 16);   // N*128 bf16
  short* Bbuf  = Abuf + (size_t)N * 128;            // N*128 bf16
  short* wb    = Bbuf + (size_t)N * 128;            // packed weights

  hipMemsetAsync(var_h, 0,
                 ((size_t)N * 64 + (size_t)F * 64 + (size_t)N * 16) * sizeof(float),
                 stream);

  PackArgs pk;
  pk.jb[0] = {m1w2,            128, 4, 32};   // C_W2A
  pk.jb[1] = {m2w2,            128, 4, 32};   // C_W2B
  pk.jb[2] = {m1w3,             16, 4,  4};   // C_W3A
  pk.jb[3] = {m2w3,             16, 4,  4};   // C_W3B
  pk.jb[4] = {m1w1,            128, 2, 16};   // C_ACOMB lo (m1w1 src)
  pk.jb[5] = {m2w1 + 64 * 128, 128, 2, 16};   // C_ACOMB hi (m2w1 dst)
  pk.jb[6] = {m1w1 + 64 * 128, 128, 2, 16};   // C_W1AD
  pk.jb[7] = {m2w1,            128, 2, 16};   // C_W1BS
  pk.jb[8] = {row1,            128, 2, 16};   // C_RO1
  pk.jb[9] = {row2,            128, 4, 32};   // C_RO2
  pk.Qw = Qw; pk.Qb = Qb;
  pk.g1wih = g1wih; pk.g1whh = g1whh;
  pk.g2wih = g2wih; pk.g2whh = g2whh;
  const int packTotal = TOTAL_CHUNKS * 512;
  k_pack<<<(packTotal + 255) / 256, 256, 0, stream>>>(pk, wb, packTotal);

  const int gN = (N + 63) / 64;
  const int gE = (E + 63) / 64;

  for (int step = 0; step < NSTEPS; ++step) {
    k_phaseA<<<gN, 256, 0, stream>>>(
        step ? msgV : nullptr, msgV, var_h, Abuf, Bbuf, wb, g2bih, g2bhh, N);
    k_phaseB<<<gE, 256, 0, stream>>>(
        Abuf, Bbuf, v2f_src, f2v_dst, feat_v2f, feat_f2v,
        m1b1, m1b2, m1b3, m2b1, m2b2, m2b3, g1bih, g1bhh,
        wb, fac_h, msgV, E, F);
  }

  k_readout_f<<<gN, 256, 0, stream>>>(
      msgV, var_h, wb, g2bih, g2bhh, rob1, rob2, row3, rob3, (float*)d_out, N);
}

// Round 10
// 918.590 us; speedup vs baseline: 1.1296x; 1.1296x over previous
//
#include <hip/hip_runtime.h>

#define NSTEPS 10

typedef __attribute__((ext_vector_type(8))) short bf16x8;
typedef __attribute__((ext_vector_type(4))) float f32x4;

__device__ __forceinline__ float sigmoidf_(float x) { return 1.0f / (1.0f + __expf(-x)); }
__device__ __forceinline__ float tanh_fast(float x) {
  const float e = __expf(2.f * x);
  return 1.f - 2.f / (e + 1.f);
}
__device__ __forceinline__ short bf16_(float x) {   // RNE, pack phase
  union { float f; unsigned u; } c; c.f = x;
  unsigned r = (c.u + 0x7FFFu + ((c.u >> 16) & 1u)) >> 16;
  return (short)r;
}
__device__ __forceinline__ unsigned pk2_(float a, float b) {  // [lo:a|hi:b]
  union { float f; unsigned u; } ca, cb; ca.f = a; cb.f = b;
  return __builtin_amdgcn_perm(cb.u + 0x8000u, ca.u + 0x8000u, 0x07060302u);
}
__device__ __forceinline__ short pk1_(float a) {
  union { float f; unsigned u; } c; c.f = a;
  return (short)((c.u + 0x8000u) >> 16);
}
__device__ __forceinline__ float lo_(unsigned u) { union { unsigned u; float f; } c; c.u = u << 16; return c.f; }
__device__ __forceinline__ float hi_(unsigned u) { union { unsigned u; float f; } c; c.u = u & 0xffff0000u; return c.f; }

__device__ __forceinline__ f32x4 mfma_16x16x32(bf16x8 a, bf16x8 b, f32x4 c) {
  return __builtin_amdgcn_mfma_f32_16x16x32_bf16(a, b, c, 0, 0, 0);
}

// chunk table (1 chunk = 512 bf16)
#define C_W2A   0
#define C_W2B   32
#define C_W3A   64
#define C_W3B   68
#define C_ACOMB 72     // [m1w1 src (16)] + [m2w1 dst (16)]
#define C_W1AD  104
#define C_W1BS  120
#define C_RO1   136
#define C_RO2   152
#define C_Q     184
#define C_G1    189
#define C_G2    237
#define TOTAL_CHUNKS 285

struct PackJob { const float* src; int N; int KS; int nchunks; };
struct PackArgs {
  PackJob jb[10];
  const float* Qw; const float* Qb;
  const float* g1wih; const float* g1whh;
  const float* g2wih; const float* g2whh;
};

__device__ __forceinline__ float pack_val(const PackArgs& a, int g) {
  int c = g >> 9;
  const int r = g & 511;
  const int j = r & 7, n = (r >> 3) & 15, q = (r >> 7) & 3;
  const int kq = q * 8 + j;
  float val = 0.f;
  bool done = false;
  #pragma unroll
  for (int ji = 0; ji < 10; ++ji) {
    if (!done && c < a.jb[ji].nchunks) {
      const int ks = c % a.jb[ji].KS;
      const int nt = c / a.jb[ji].KS;
      const int k = ks * 32 + kq;
      val = a.jb[ji].src[(size_t)k * a.jb[ji].N + nt * 16 + n];
      done = true;
    }
    if (!done) c -= a.jb[ji].nchunks;
  }
  if (!done) {
    if (c < 5) {  // q-transform (K padded 16->32)
      val = 0.f;
      if (kq < 16) val = (c < 4) ? a.Qw[c * 256 + n * 16 + kq] : a.Qb[n * 16 + kq];
    } else {      // GRU: 256 cols = [r|z|in|hn], K=96; s-remap: s = (nq&15)*4 + (nq>>4)
      c -= 5;
      const float* wih = (c < 48) ? a.g1wih : a.g2wih;
      const float* whh = (c < 48) ? a.g1whh : a.g2whh;
      if (c >= 48) c -= 48;
      const int nt = c / 3, ks = c % 3;
      const int k = ks * 32 + kq;
      const int ng = nt * 16 + n;
      const int gate = ng >> 6;
      const int nq = ng & 63;
      const int s = (nq & 15) * 4 + (nq >> 4);
      val = 0.f;
      if (gate == 0) {
        if (k < 16) val = wih[k * 192 + s];
        else if (k < 80) val = whh[(k - 16) * 192 + s];
      } else if (gate == 1) {
        if (k < 16) val = wih[k * 192 + 64 + s];
        else if (k < 80) val = whh[(k - 16) * 192 + 64 + s];
      } else if (gate == 2) {
        if (k < 16) val = wih[k * 192 + 128 + s];
      } else {
        if (k >= 16 && k < 80) val = whh[(k - 16) * 192 + 128 + s];
      }
    }
  }
  return val;
}

__global__ __launch_bounds__(256) void k_pack(PackArgs a, short* __restrict__ out, int total) {
  const int g = blockIdx.x * 256 + threadIdx.x;
  if (g < total) out[g] = bf16_(pack_val(a, g));
}

// ---------------------------------------------------------------------------
// var GRU tile (s-remapped): lane owns cols sb=m*4..+3; vector epilogue.
// ---------------------------------------------------------------------------
__device__ __forceinline__ void var_gru_tile(
    const short* wb, const float* gbih, const float* gbhh,
    const short* SA, float* gruH, short* outTile, int outStr,
    int rbase, int Nn, int lane, int wave, int m, int quad, bool writeH)
{
  f32x4 acc[16] = {};
  #pragma unroll
  for (int ks = 0; ks < 3; ++ks) {
    const bf16x8 av = *(const bf16x8*)&SA[(wave * 16 + m) * 104 + ks * 32 + quad * 8];
    #pragma unroll
    for (int nt = 0; nt < 16; ++nt)
      acc[nt] = mfma_16x16x32(av, ((const bf16x8*)(wb + C_G2 * 512))[(nt * 3 + ks) * 64 + lane], acc[nt]);
  }
  const int sb = m * 4;
  const f32x4 bir = *(const f32x4*)(gbih + sb);
  const f32x4 bhr = *(const f32x4*)(gbhh + sb);
  const f32x4 biz = *(const f32x4*)(gbih + 64 + sb);
  const f32x4 bhz = *(const f32x4*)(gbhh + 64 + sb);
  const f32x4 bi4 = *(const f32x4*)(gbih + 128 + sb);
  const f32x4 bh4 = *(const f32x4*)(gbhh + 128 + sb);
  #pragma unroll
  for (int reg = 0; reg < 4; ++reg) {
    const int lr = wave * 16 + quad * 4 + reg, rg = rbase + lr;
    uint2 pv; pv.x = 0u; pv.y = 0u;
    if (rg < Nn) {
      const f32x4 ho = *(const f32x4*)(gruH + (size_t)rg * 64 + sb);
      f32x4 hn;
      #pragma unroll
      for (int nt = 0; nt < 4; ++nt) {
        const float rr = sigmoidf_(acc[nt][reg] + bir[nt] + bhr[nt]);
        const float zz = sigmoidf_(acc[4 + nt][reg] + biz[nt] + bhz[nt]);
        const float nn = tanh_fast(acc[8 + nt][reg] + bi4[nt] + rr * (acc[12 + nt][reg] + bh4[nt]));
        hn[nt] = (1.f - zz) * nn + zz * ho[nt];
      }
      if (writeH) *(f32x4*)(gruH + (size_t)rg * 64 + sb) = hn;
      pv.x = pk2_(hn[0], hn[1]);
      pv.y = pk2_(hn[2], hn[3]);
    }
    *(uint2*)&outTile[lr * outStr + sb] = pv;
  }
}

// ---------------------------------------------------------------------------
// transposed 128-col partial from an LDS tile: Ps[fac][col] = src @ W.
// ---------------------------------------------------------------------------
__device__ __forceinline__ void partial_gemm_T(
    const short* chunk, const short* srcTile, int srcStr, short* Ps,
    int lane, int wave, int m, int quad)
{
  const int nt = wave & 1, mt0 = (wave >> 1) * 4;
  f32x4 acc[4] = {};
  #pragma unroll
  for (int ks = 0; ks < 2; ++ks) {
    const bf16x8 bfr = *(const bf16x8*)&srcTile[(nt * 16 + m) * srcStr + ks * 32 + quad * 8];
    #pragma unroll
    for (int j = 0; j < 4; ++j)
      acc[j] = mfma_16x16x32(((const bf16x8*)chunk)[((mt0 + j) * 2 + ks) * 64 + lane], bfr, acc[j]);
  }
  #pragma unroll
  for (int j = 0; j < 4; ++j) {
    const int col = (mt0 + j) * 16 + quad * 4;
    uint2 pv;
    pv.x = pk2_(acc[j][0], acc[j][1]);
    pv.y = pk2_(acc[j][2], acc[j][3]);
    *(uint2*)&Ps[(nt * 16 + m) * 136 + col] = pv;
  }
}

// ---------------------------------------------------------------------------
// edge MLP tail, transposed L2. One internal barrier (protects ms/Ps overlay);
// h1/h2/ms rows wave-private otherwise. feats direct from global.
// ---------------------------------------------------------------------------
__device__ __forceinline__ void edge_tail(
    const short* wb, int cw2, int cw3,
    const float* b2, const float* b3,
    short* h1s, short* ms, const float* feat_g, int e0, int E,
    int lane, int wave, int m, int quad, float* mq)
{
  {
    f32x4 acc[8] = {};
    #pragma unroll
    for (int ks = 0; ks < 4; ++ks) {
      const bf16x8 bfr = *(const bf16x8*)&h1s[(wave * 16 + m) * 136 + ks * 32 + quad * 8];
      #pragma unroll
      for (int mt = 0; mt < 8; ++mt)
        acc[mt] = mfma_16x16x32(((const bf16x8*)(wb + cw2))[(mt * 4 + ks) * 64 + lane], bfr, acc[mt]);
    }
    #pragma unroll
    for (int mt = 0; mt < 8; ++mt) {
      const int col = mt * 16 + quad * 4;
      const f32x4 bv = *(const f32x4*)(b2 + col);
      uint2 pv;
      pv.x = pk2_(fmaxf(acc[mt][0] + bv[0], 0.f), fmaxf(acc[mt][1] + bv[1], 0.f));
      pv.y = pk2_(fmaxf(acc[mt][2] + bv[2], 0.f), fmaxf(acc[mt][3] + bv[3], 0.f));
      *(uint2*)&h1s[(wave * 16 + m) * 136 + col] = pv;
    }
  }
  __syncthreads();   // all waves done with Ps reads before ms (overlay) writes

  f32x4 acc3 = {};
  #pragma unroll
  for (int ks = 0; ks < 4; ++ks) {
    const bf16x8 afr = *(const bf16x8*)&h1s[(wave * 16 + m) * 136 + ks * 32 + quad * 8];
    acc3 = mfma_16x16x32(afr, ((const bf16x8*)(wb + cw3))[ks * 64 + lane], acc3);
  }
  const float b3v = b3[m];
  #pragma unroll
  for (int rr = 0; rr < 4; ++rr) {
    const int row = wave * 16 + quad * 4 + rr;
    ms[row * 40 + m] = pk1_(acc3[rr] + b3v);
    ms[row * 40 + 16 + m] = 0;
  }
  // no barrier: ms rows wave-private, DS in-order per wave

  f32x4 accY[5] = {};
  {
    const bf16x8 afr = *(const bf16x8*)&ms[(wave * 16 + m) * 40 + quad * 8];
    #pragma unroll
    for (int tq = 0; tq < 5; ++tq)
      accY[tq] = mfma_16x16x32(afr, ((const bf16x8*)(wb + C_Q * 512))[tq * 64 + lane], accY[tq]);
  }
  #pragma unroll
  for (int rr = 0; rr < 4; ++rr) {
    const int row = wave * 16 + quad * 4 + rr;
    const int er = e0 + row;
    const f32x4 f = *(const f32x4*)(feat_g + (size_t)(er < E ? er : 0) * 4);
    mq[rr] = accY[4][rr] + f.x * accY[0][rr] + f.y * accY[1][rr]
                         + f.z * accY[2][rr] + f.w * accY[3][rr];
  }
}

// ---------------------------------------------------------------------------
// k_phaseA: var GRU (if msgIn) + transposed combined partials -> Abuf/Bbuf.
// ---------------------------------------------------------------------------
__global__ __launch_bounds__(256) void k_phaseA(
    const float* __restrict__ msgIn, float* __restrict__ msgZero,
    float* __restrict__ var_h,
    short* __restrict__ Abuf, short* __restrict__ Bbuf,
    const short* __restrict__ wb,
    const float* __restrict__ gbih, const float* __restrict__ gbhh, int N)
{
  __shared__ short SA[64 * 104];
  __shared__ short Xs[64 * 72];
  const int t = threadIdx.x, lane = t & 63, wave = t >> 6;
  const int m = lane & 15, quad = lane >> 4;
  const int rbase = blockIdx.x * 64;

  if (msgIn) {
    {
      const int r = t >> 2, q4 = t & 3, rg = rbase + r;
      #pragma unroll
      for (int i = 0; i < 6; ++i) {
        const int c = q4 * 4 + i * 16;
        f32x4 v = {0.f, 0.f, 0.f, 0.f};
        if (rg < N) {
          if (c < 16)      v = *(const f32x4*)(msgIn + (size_t)rg * 16 + c);
          else if (c < 80) v = *(const f32x4*)(var_h + (size_t)rg * 64 + (c - 16));
        }
        *(unsigned*)&SA[r * 104 + c]     = pk2_(v.x, v.y);
        *(unsigned*)&SA[r * 104 + c + 2] = pk2_(v.z, v.w);
      }
      if (rbase + r < N) {
        f32x4 z = {0.f, 0.f, 0.f, 0.f};
        *(f32x4*)(msgZero + (size_t)(rbase + r) * 16 + q4 * 4) = z;
      }
    }
    __syncthreads();
    var_gru_tile(wb, gbih, gbhh, SA, var_h, Xs, 72,
                 rbase, N, lane, wave, m, quad, true);
    __syncthreads();
  } else {
    const int r = t >> 2, q4 = t & 3, rg = rbase + r;
    #pragma unroll
    for (int i = 0; i < 4; ++i) {
      const int cc = q4 * 4 + i * 16;
      f32x4 v = {0.f, 0.f, 0.f, 0.f};
      if (rg < N) v = *(const f32x4*)(var_h + (size_t)rg * 64 + cc);
      *(unsigned*)&Xs[r * 72 + cc]     = pk2_(v.x, v.y);
      *(unsigned*)&Xs[r * 72 + cc + 2] = pk2_(v.z, v.w);
    }
    __syncthreads();
  }

  // transposed combined GEMM: D[col 0..255][row]; wave = row-tile
  f32x4 acc[16] = {};
  #pragma unroll
  for (int ks = 0; ks < 2; ++ks) {
    const bf16x8 bfr = *(const bf16x8*)&Xs[(wave * 16 + m) * 72 + ks * 32 + quad * 8];
    #pragma unroll
    for (int mt = 0; mt < 16; ++mt)
      acc[mt] = mfma_16x16x32(((const bf16x8*)(wb + C_ACOMB * 512))[(mt * 2 + ks) * 64 + lane], bfr, acc[mt]);
  }
  const int rg = rbase + wave * 16 + m;
  if (rg < N) {
    #pragma unroll
    for (int mt = 0; mt < 16; ++mt) {
      const int col = mt * 16 + quad * 4;
      short* dst = (col < 128) ? Abuf : Bbuf;
      uint2 pv;
      pv.x = pk2_(acc[mt][0], acc[mt][1]);
      pv.y = pk2_(acc[mt][2], acc[mt][3]);
      *(uint2*)&dst[(size_t)rg * 128 + (col & 127)] = pv;
    }
  }
}

// ---------------------------------------------------------------------------
// k_phaseB: v2f edge + factor GRU + f2v edge. 32768 B LDS (5 blocks/CU by
// LDS); no register prefetch across barriers; 6 barriers total.
// ---------------------------------------------------------------------------
__global__ __launch_bounds__(256) void k_phaseB(
    const short* __restrict__ Abuf, const short* __restrict__ Bbuf,
    const int* __restrict__ v2f_src, const int* __restrict__ f2v_dst,
    const float* __restrict__ featA, const float* __restrict__ featB,
    const float* __restrict__ m1b1, const float* __restrict__ m1b2,
    const float* __restrict__ m1b3,
    const float* __restrict__ m2b1, const float* __restrict__ m2b2,
    const float* __restrict__ m2b3,
    const float* __restrict__ g1bih, const float* __restrict__ g1bhh,
    const short* __restrict__ wb,
    float* __restrict__ fac_h, float* __restrict__ msgV, int E, int F)
{
  __shared__ __align__(16) char smemB[32768];
  short* h1s = (short*)(smemB);            // 64*136*2 = 17408
  short* Ps  = (short*)(smemB + 17408);    // 32*136*2 = 8704  (ms overlays)
  short* ms  = (short*)(smemB + 17408);    // 64*40*2  = 5120
  short* Fs2 = (short*)(smemB);            // 32*72*2  = 4608  (overlays h1s)
  short* AsG = (short*)(smemB + 26112);    // 32*104*2 = 6656  -> 32768 total

  const int t = threadIdx.x, lane = t & 63, wave = t >> 6;
  const int m = lane & 15, quad = lane >> 4;
  const int e0 = blockIdx.x * 64, f0 = blockIdx.x * 32;
  const int r = t >> 2, q4 = t & 3;

  // indices only (6 scalar regs) — gathers read at use site
  const bool okR = (e0 + r) < E;
  const int sidx_r = okR ? v2f_src[e0 + r] : 0;
  const int didx_r = okR ? f2v_dst[e0 + r] : 0;
  int aidx[4];
  #pragma unroll
  for (int rr = 0; rr < 4; ++rr) {
    const int er = e0 + wave * 16 + quad * 4 + rr;
    aidx[rr] = (er < E) ? f2v_dst[er] : 0;
  }

  // ---- S0: stage fac_h -> AsG [pad16|h64|pad16-zero] (needed at GRU only) ----
  {
    const int hr = t >> 3, hc = (t & 7) * 8;
    const int f = f0 + hr;
    f32x4 a0 = {0.f,0.f,0.f,0.f}, a1 = {0.f,0.f,0.f,0.f};
    if (f < F) {
      a0 = *(const f32x4*)(fac_h + (size_t)f * 64 + hc);
      a1 = *(const f32x4*)(fac_h + (size_t)f * 64 + hc + 4);
    }
    uint4 o;
    o.x = pk2_(a0.x, a0.y); o.y = pk2_(a0.z, a0.w);
    o.z = pk2_(a1.x, a1.y); o.w = pk2_(a1.z, a1.w);
    *(uint4*)&AsG[hr * 104 + 16 + hc] = o;
    if (t < 64) {
      uint4 z = make_uint4(0u, 0u, 0u, 0u);
      *(uint4*)&AsG[(t >> 1) * 104 + 80 + (t & 1) * 8] = z;
    }
  }

  // ---- S1: local v2f dst-partial, B-operand DIRECT from global fac_h ----
  {
    const int nt = wave & 1, mt0 = (wave >> 1) * 4;
    const int f = f0 + nt * 16 + m;
    f32x4 acc[4] = {};
    #pragma unroll
    for (int ks = 0; ks < 2; ++ks) {
      f32x4 v0 = {0.f,0.f,0.f,0.f}, v1 = {0.f,0.f,0.f,0.f};
      if (f < F) {
        v0 = *(const f32x4*)(fac_h + (size_t)f * 64 + ks * 32 + quad * 8);
        v1 = *(const f32x4*)(fac_h + (size_t)f * 64 + ks * 32 + quad * 8 + 4);
      }
      union { unsigned u[4]; bf16x8 v; } cvt;
      cvt.u[0] = pk2_(v0.x, v0.y); cvt.u[1] = pk2_(v0.z, v0.w);
      cvt.u[2] = pk2_(v1.x, v1.y); cvt.u[3] = pk2_(v1.z, v1.w);
      #pragma unroll
      for (int j = 0; j < 4; ++j)
        acc[j] = mfma_16x16x32(
            ((const bf16x8*)(wb + C_W1AD * 512))[((mt0 + j) * 2 + ks) * 64 + lane],
            cvt.v, acc[j]);
    }
    #pragma unroll
    for (int j = 0; j < 4; ++j) {
      const int col = (mt0 + j) * 16 + quad * 4;
      uint2 pv;
      pv.x = pk2_(acc[j][0], acc[j][1]);
      pv.y = pk2_(acc[j][2], acc[j][3]);
      *(uint2*)&Ps[(nt * 16 + m) * 136 + col] = pv;
    }
  }
  __syncthreads();                                                   // [1]

  // ---- S2: v2f h1 = relu(Abuf[src] + Ps[e>>1] + m1b1) ----
  {
    const short* pa = Abuf + (size_t)sidx_r * 128;
    const short* pb = Ps + (r >> 1) * 136;
    #pragma unroll
    for (int i = 0; i < 4; ++i) {
      const int col = (q4 + i * 4) * 8;
      uint4 o = make_uint4(0u, 0u, 0u, 0u);
      if (okR) {
        const uint4 ua = *(const uint4*)(pa + col);
        const uint4 ub = *(const uint4*)(pb + col);
        const f32x4 ba = *(const f32x4*)(m1b1 + col);
        const f32x4 bb = *(const f32x4*)(m1b1 + col + 4);
        o.x = pk2_(fmaxf(lo_(ua.x) + lo_(ub.x) + ba.x, 0.f),
                   fmaxf(hi_(ua.x) + hi_(ub.x) + ba.y, 0.f));
        o.y = pk2_(fmaxf(lo_(ua.y) + lo_(ub.y) + ba.z, 0.f),
                   fmaxf(hi_(ua.y) + hi_(ub.y) + ba.w, 0.f));
        o.z = pk2_(fmaxf(lo_(ua.z) + lo_(ub.z) + bb.x, 0.f),
                   fmaxf(hi_(ua.z) + hi_(ub.z) + bb.y, 0.f));
        o.w = pk2_(fmaxf(lo_(ua.w) + lo_(ub.w) + bb.z, 0.f),
                   fmaxf(hi_(ua.w) + hi_(ub.w) + bb.w, 0.f));
      }
      *(uint4*)&h1s[r * 136 + col] = o;
    }
  }
  // no barrier: h1 rows wave-private

  // ---- edge tail 1 (internal barrier [2]) ----
  float mq[4];
  edge_tail(wb, C_W2A * 512, C_W3A * 512, m1b2, m1b3,
            h1s, ms, featA, e0, E, lane, wave, m, quad, mq);
  {
    const int fl = wave * 8 + quad * 2;
    AsG[fl * 104 + m]       = pk1_(mq[0] + mq[1]);
    AsG[(fl + 1) * 104 + m] = pk1_(mq[2] + mq[3]);
  }
  __syncthreads();                                                   // [3]

  // ---- factor GRU on 32 local rows ----
  {
    const int mtg = wave >> 1, sh = wave & 1;
    f32x4 accG[8] = {};
    #pragma unroll
    for (int ks = 0; ks < 3; ++ks) {
      const bf16x8 av = *(const bf16x8*)&AsG[(mtg * 16 + m) * 104 + ks * 32 + quad * 8];
      #pragma unroll
      for (int g = 0; g < 4; ++g)
        #pragma unroll
        for (int nt2 = 0; nt2 < 2; ++nt2) {
          const int nt = g * 4 + sh * 2 + nt2;
          accG[g * 2 + nt2] = mfma_16x16x32(
              av, ((const bf16x8*)(wb + C_G1 * 512))[(nt * 3 + ks) * 64 + lane],
              accG[g * 2 + nt2]);
        }
    }
    const int sb = m * 4 + sh * 2;
    const float br0 = g1bih[sb] + g1bhh[sb],           br1 = g1bih[sb + 1] + g1bhh[sb + 1];
    const float bz0 = g1bih[64 + sb] + g1bhh[64 + sb], bz1 = g1bih[65 + sb] + g1bhh[65 + sb];
    const float bi0 = g1bih[128 + sb], bi1 = g1bih[129 + sb];
    const float bh0 = g1bhh[128 + sb], bh1 = g1bhh[129 + sb];
    #pragma unroll
    for (int reg = 0; reg < 4; ++reg) {
      const int lr = mtg * 16 + quad * 4 + reg;
      const int f = f0 + lr;
      float hn0 = 0.f, hn1 = 0.f;
      if (f < F) {
        const float2 ho = *(const float2*)(fac_h + (size_t)f * 64 + sb);
        const float r0 = sigmoidf_(accG[0][reg] + br0);
        const float r1 = sigmoidf_(accG[1][reg] + br1);
        const float z0 = sigmoidf_(accG[2][reg] + bz0);
        const float z1 = sigmoidf_(accG[3][reg] + bz1);
        const float n0 = tanh_fast(accG[4][reg] + bi0 + r0 * (accG[6][reg] + bh0));
        const float n1 = tanh_fast(accG[5][reg] + bi1 + r1 * (accG[7][reg] + bh1));
        hn0 = (1.f - z0) * n0 + z0 * ho.x;
        hn1 = (1.f - z1) * n1 + z1 * ho.y;
        float2 hw; hw.x = hn0; hw.y = hn1;
        *(float2*)(fac_h + (size_t)f * 64 + sb) = hw;
      }
      *(unsigned*)&Fs2[lr * 72 + sb] = pk2_(hn0, hn1);
    }
  }
  __syncthreads();                                                   // [4]

  // ---- local f2v src-partial from Fs2 ----
  partial_gemm_T(wb + C_W1BS * 512, Fs2, 72, Ps, lane, wave, m, quad);
  __syncthreads();                                                   // [5]

  // ---- f2v h1 = relu(Ps[e>>1] + Bbuf[dst] + m2b1) ----
  {
    const short* pa = Ps + (r >> 1) * 136;
    const short* pb = Bbuf + (size_t)didx_r * 128;
    #pragma unroll
    for (int i = 0; i < 4; ++i) {
      const int col = (q4 + i * 4) * 8;
      uint4 o = make_uint4(0u, 0u, 0u, 0u);
      if (okR) {
        const uint4 ua = *(const uint4*)(pa + col);
        const uint4 ub = *(const uint4*)(pb + col);
        const f32x4 ba = *(const f32x4*)(m2b1 + col);
        const f32x4 bb = *(const f32x4*)(m2b1 + col + 4);
        o.x = pk2_(fmaxf(lo_(ua.x) + lo_(ub.x) + ba.x, 0.f),
                   fmaxf(hi_(ua.x) + hi_(ub.x) + ba.y, 0.f));
        o.y = pk2_(fmaxf(lo_(ua.y) + lo_(ub.y) + ba.z, 0.f),
                   fmaxf(hi_(ua.y) + hi_(ub.y) + ba.w, 0.f));
        o.z = pk2_(fmaxf(lo_(ua.z) + lo_(ub.z) + bb.x, 0.f),
                   fmaxf(hi_(ua.z) + hi_(ub.z) + bb.y, 0.f));
        o.w = pk2_(fmaxf(lo_(ua.w) + lo_(ub.w) + bb.z, 0.f),
                   fmaxf(hi_(ua.w) + hi_(ub.w) + bb.w, 0.f));
      }
      *(uint4*)&h1s[r * 136 + col] = o;
    }
  }
  // no barrier: h1 rows wave-private

  // ---- edge tail 2 (internal barrier [6]) + atomics ----
  float mq2[4];
  edge_tail(wb, C_W2B * 512, C_W3B * 512, m2b2, m2b3,
            h1s, ms, featB, e0, E, lane, wave, m, quad, mq2);
  #pragma unroll
  for (int rr = 0; rr < 4; ++rr) {
    const int erow = wave * 16 + quad * 4 + rr;
    if (e0 + erow < E)
      atomicAdd(msgV + (size_t)aidx[rr] * 16 + m, mq2[rr]);
  }
}

// ---------------------------------------------------------------------------
// k_readout_f: final var GRU + RO1 + RO2 (transposed) + RO3 + softmax.
// ---------------------------------------------------------------------------
__global__ __launch_bounds__(256) void k_readout_f(
    const float* __restrict__ gruMsg, const float* __restrict__ gruH,
    const short* __restrict__ wb,
    const float* __restrict__ gbih, const float* __restrict__ gbhh,
    const float* __restrict__ rob1, const float* __restrict__ rob2,
    const float* __restrict__ row3, const float* __restrict__ rob3,
    float* __restrict__ out, int rows)
{
  __shared__ short SA[64 * 104];
  __shared__ short SH[64 * 72];
  __shared__ short S1[64 * 136];
  __shared__ short S2[64 * 136];
  __shared__ float w3s[256];
  const int t = threadIdx.x, lane = t & 63, wave = t >> 6;
  const int m = lane & 15, quad = lane >> 4;
  const int rbase = blockIdx.x * 64;

  w3s[t] = row3[t];
  {
    const int r = t >> 2, q4 = t & 3, rg = rbase + r;
    #pragma unroll
    for (int i = 0; i < 6; ++i) {
      const int c = q4 * 4 + i * 16;
      f32x4 v = {0.f, 0.f, 0.f, 0.f};
      if (rg < rows) {
        if (c < 16)      v = *(const f32x4*)(gruMsg + (size_t)rg * 16 + c);
        else if (c < 80) v = *(const f32x4*)(gruH + (size_t)rg * 64 + (c - 16));
      }
      *(unsigned*)&SA[r * 104 + c]     = pk2_(v.x, v.y);
      *(unsigned*)&SA[r * 104 + c + 2] = pk2_(v.z, v.w);
    }
  }
  __syncthreads();
  var_gru_tile(wb, gbih, gbhh, SA, (float*)gruH, SH, 72,
               rbase, rows, lane, wave, m, quad, false);
  __syncthreads();

  // RO1 (transposed)
  {
    f32x4 acc[8] = {};
    #pragma unroll
    for (int ks = 0; ks < 2; ++ks) {
      const bf16x8 bfr = *(const bf16x8*)&SH[(wave * 16 + m) * 72 + ks * 32 + quad * 8];
      #pragma unroll
      for (int mt = 0; mt < 8; ++mt)
        acc[mt] = mfma_16x16x32(((const bf16x8*)(wb + C_RO1 * 512))[(mt * 2 + ks) * 64 + lane], bfr, acc[mt]);
    }
    #pragma unroll
    for (int mt = 0; mt < 8; ++mt) {
      const int col = mt * 16 + quad * 4;
      const f32x4 bv = *(const f32x4*)(rob1 + col);
      uint2 pv;
      pv.x = pk2_(fmaxf(acc[mt][0] + bv[0], 0.f), fmaxf(acc[mt][1] + bv[1], 0.f));
      pv.y = pk2_(fmaxf(acc[mt][2] + bv[2], 0.f), fmaxf(acc[mt][3] + bv[3], 0.f));
      *(uint2*)&S1[(wave * 16 + m) * 136 + col] = pv;
    }
  }
  __syncthreads();

  // RO2 (transposed)
  {
    f32x4 acc[8] = {};
    #pragma unroll
    for (int ks = 0; ks < 4; ++ks) {
      const bf16x8 bfr = *(const bf16x8*)&S1[(wave * 16 + m) * 136 + ks * 32 + quad * 8];
      #pragma unroll
      for (int mt = 0; mt < 8; ++mt)
        acc[mt] = mfma_16x16x32(((const bf16x8*)(wb + C_RO2 * 512))[(mt * 4 + ks) * 64 + lane], bfr, acc[mt]);
    }
    #pragma unroll
    for (int mt = 0; mt < 8; ++mt) {
      const int col = mt * 16 + quad * 4;
      const f32x4 bv = *(const f32x4*)(rob2 + col);
      uint2 pv;
      pv.x = pk2_(fmaxf(acc[mt][0] + bv[0], 0.f), fmaxf(acc[mt][1] + bv[1], 0.f));
      pv.y = pk2_(fmaxf(acc[mt][2] + bv[2], 0.f), fmaxf(acc[mt][3] + bv[3], 0.f));
      *(uint2*)&S2[(wave * 16 + m) * 136 + col] = pv;
    }
  }
  __syncthreads();

  if (t < 64) {
    const int rg = rbase + t;
    if (rg < rows) {
      float l0 = rob3[0], l1 = rob3[1];
      #pragma unroll 8
      for (int k = 0; k < 128; k += 2) {
        const unsigned u = *(const unsigned*)&S2[t * 136 + k];
        const float x0 = lo_(u), x1 = hi_(u);
        l0 = fmaf(x0, w3s[k * 2 + 0], l0);
        l1 = fmaf(x0, w3s[k * 2 + 1], l1);
        l0 = fmaf(x1, w3s[k * 2 + 2], l0);
        l1 = fmaf(x1, w3s[k * 2 + 3], l1);
      }
      const float mx = fmaxf(l0, l1);
      const float e0 = __expf(l0 - mx), e1 = __expf(l1 - mx);
      const float inv = 1.f / (e0 + e1);
      out[(size_t)rg * 2 + 0] = e0 * inv;
      out[(size_t)rg * 2 + 1] = e1 * inv;
    }
  }
}

// ---------------------------------------------------------------------------
extern "C" void kernel_launch(void* const* d_in, const int* in_sizes, int n_in,
                              void* d_out, int out_size, void* d_ws, size_t ws_size,
                              hipStream_t stream)
{
  const int*   v2f_src  = (const int*)d_in[0];
  const int*   f2v_dst  = (const int*)d_in[3];
  const float* feat_v2f = (const float*)d_in[4];
  const float* feat_f2v = (const float*)d_in[5];
  const float* Qw    = (const float*)d_in[8];
  const float* Qb    = (const float*)d_in[9];
  const float* m1w1  = (const float*)d_in[10];
  const float* m1b1  = (const float*)d_in[11];
  const float* m1w2  = (const float*)d_in[12];
  const float* m1b2  = (const float*)d_in[13];
  const float* m1w3  = (const float*)d_in[14];
  const float* m1b3  = (const float*)d_in[15];
  const float* m2w1  = (const float*)d_in[16];
  const float* m2b1  = (const float*)d_in[17];
  const float* m2w2  = (const float*)d_in[18];
  const float* m2b2  = (const float*)d_in[19];
  const float* m2w3  = (const float*)d_in[20];
  const float* m2b3  = (const float*)d_in[21];
  const float* g1wih = (const float*)d_in[22];
  const float* g1whh = (const float*)d_in[23];
  const float* g1bih = (const float*)d_in[24];
  const float* g1bhh = (const float*)d_in[25];
  const float* g2wih = (const float*)d_in[26];
  const float* g2whh = (const float*)d_in[27];
  const float* g2bih = (const float*)d_in[28];
  const float* g2bhh = (const float*)d_in[29];
  const float* row1  = (const float*)d_in[30];
  const float* rob1  = (const float*)d_in[31];
  const float* row2  = (const float*)d_in[32];
  const float* rob2  = (const float*)d_in[33];
  const float* row3  = (const float*)d_in[34];
  const float* rob3  = (const float*)d_in[35];

  const int E = in_sizes[0];
  const int N = out_size / 2;
  const int F = E / 2;

  float* wsf   = (float*)d_ws;
  float* var_h = wsf;                               // N*64
  float* fac_h = var_h + (size_t)N * 64;            // F*64
  float* msgV  = fac_h + (size_t)F * 64;            // N*16
  short* Abuf  = (short*)(msgV + (size_t)N * 16);   // N*128 bf16
  short* Bbuf  = Abuf + (size_t)N * 128;            // N*128 bf16
  short* wb    = Bbuf + (size_t)N * 128;            // packed weights

  hipMemsetAsync(var_h, 0,
                 ((size_t)N * 64 + (size_t)F * 64 + (size_t)N * 16) * sizeof(float),
                 stream);

  PackArgs pk;
  pk.jb[0] = {m1w2,            128, 4, 32};   // C_W2A
  pk.jb[1] = {m2w2,            128, 4, 32};   // C_W2B
  pk.jb[2] = {m1w3,             16, 4,  4};   // C_W3A
  pk.jb[3] = {m2w3,             16, 4,  4};   // C_W3B
  pk.jb[4] = {m1w1,            128, 2, 16};   // C_ACOMB lo (m1w1 src)
  pk.jb[5] = {m2w1 + 64 * 128, 128, 2, 16};   // C_ACOMB hi (m2w1 dst)
  pk.jb[6] = {m1w1 + 64 * 128, 128, 2, 16};   // C_W1AD
  pk.jb[7] = {m2w1,            128, 2, 16};   // C_W1BS
  pk.jb[8] = {row1,            128, 2, 16};   // C_RO1
  pk.jb[9] = {row2,            128, 4, 32};   // C_RO2
  pk.Qw = Qw; pk.Qb = Qb;
  pk.g1wih = g1wih; pk.g1whh = g1whh;
  pk.g2wih = g2wih; pk.g2whh = g2whh;
  const int packTotal = TOTAL_CHUNKS * 512;
  k_pack<<<(packTotal + 255) / 256, 256, 0, stream>>>(pk, wb, packTotal);

  const int gN = (N + 63) / 64;
  const int gE = (E + 63) / 64;

  for (int step = 0; step < NSTEPS; ++step) {
    k_phaseA<<<gN, 256, 0, stream>>>(
        step ? msgV : nullptr, msgV, var_h, Abuf, Bbuf, wb, g2bih, g2bhh, N);
    k_phaseB<<<gE, 256, 0, stream>>>(
        Abuf, Bbuf, v2f_src, f2v_dst, feat_v2f, feat_f2v,
        m1b1, m1b2, m1b3, m2b1, m2b2, m2b3, g1bih, g1bhh,
        wb, fac_h, msgV, E, F);
  }

  k_readout_f<<<gN, 256, 0, stream>>>(
      msgV, var_h, wb, g2bih, g2bhh, rob1, rob2, row3, rob3, (float*)d_out, N);
}

// Round 11
// 858.315 us; speedup vs baseline: 1.2090x; 1.0702x over previous
//
#include <hip/hip_runtime.h>

#define NSTEPS 10

typedef __attribute__((ext_vector_type(8))) short bf16x8;
typedef __attribute__((ext_vector_type(4))) float f32x4;

__device__ __forceinline__ float sigmoidf_(float x) { return 1.0f / (1.0f + __expf(-x)); }
__device__ __forceinline__ float tanh_fast(float x) {
  const float e = __expf(2.f * x);
  return 1.f - 2.f / (e + 1.f);
}
__device__ __forceinline__ short bf16_(float x) {   // RNE, pack phase
  union { float f; unsigned u; } c; c.f = x;
  unsigned r = (c.u + 0x7FFFu + ((c.u >> 16) & 1u)) >> 16;
  return (short)r;
}
__device__ __forceinline__ unsigned pk2_(float a, float b) {  // [lo:a|hi:b]
  union { float f; unsigned u; } ca, cb; ca.f = a; cb.f = b;
  return __builtin_amdgcn_perm(cb.u + 0x8000u, ca.u + 0x8000u, 0x07060302u);
}
__device__ __forceinline__ short pk1_(float a) {
  union { float f; unsigned u; } c; c.f = a;
  return (short)((c.u + 0x8000u) >> 16);
}
__device__ __forceinline__ float lo_(unsigned u) { union { unsigned u; float f; } c; c.u = u << 16; return c.f; }
__device__ __forceinline__ float hi_(unsigned u) { union { unsigned u; float f; } c; c.u = u & 0xffff0000u; return c.f; }

__device__ __forceinline__ f32x4 mfma_16x16x32(bf16x8 a, bf16x8 b, f32x4 c) {
  return __builtin_amdgcn_mfma_f32_16x16x32_bf16(a, b, c, 0, 0, 0);
}

// chunk table (1 chunk = 512 bf16)
#define C_W2A   0
#define C_W2B   32
#define C_W3A   64
#define C_W3B   68
#define C_ACOMB 72     // [m1w1 src (16)] + [m2w1 dst (16)]
#define C_W1AD  104
#define C_W1BS  120
#define C_RO1   136
#define C_RO2   152
#define C_Q     184
#define C_G1    189
#define C_G2    237
#define TOTAL_CHUNKS 285

struct PackJob { const float* src; int N; int KS; int nchunks; };
struct PackArgs {
  PackJob jb[10];
  const float* Qw; const float* Qb;
  const float* g1wih; const float* g1whh;
  const float* g2wih; const float* g2whh;
};

__device__ __forceinline__ float pack_val(const PackArgs& a, int g) {
  int c = g >> 9;
  const int r = g & 511;
  const int j = r & 7, n = (r >> 3) & 15, q = (r >> 7) & 3;
  const int kq = q * 8 + j;
  float val = 0.f;
  bool done = false;
  #pragma unroll
  for (int ji = 0; ji < 10; ++ji) {
    if (!done && c < a.jb[ji].nchunks) {
      const int ks = c % a.jb[ji].KS;
      const int nt = c / a.jb[ji].KS;
      const int k = ks * 32 + kq;
      val = a.jb[ji].src[(size_t)k * a.jb[ji].N + nt * 16 + n];
      done = true;
    }
    if (!done) c -= a.jb[ji].nchunks;
  }
  if (!done) {
    if (c < 5) {  // q-transform (K padded 16->32)
      val = 0.f;
      if (kq < 16) val = (c < 4) ? a.Qw[c * 256 + n * 16 + kq] : a.Qb[n * 16 + kq];
    } else {      // GRU: 256 cols = [r|z|in|hn], K=96; s-remap: s = (nq&15)*4 + (nq>>4)
      c -= 5;
      const float* wih = (c < 48) ? a.g1wih : a.g2wih;
      const float* whh = (c < 48) ? a.g1whh : a.g2whh;
      if (c >= 48) c -= 48;
      const int nt = c / 3, ks = c % 3;
      const int k = ks * 32 + kq;
      const int ng = nt * 16 + n;
      const int gate = ng >> 6;
      const int nq = ng & 63;
      const int s = (nq & 15) * 4 + (nq >> 4);
      val = 0.f;
      if (gate == 0) {
        if (k < 16) val = wih[k * 192 + s];
        else if (k < 80) val = whh[(k - 16) * 192 + s];
      } else if (gate == 1) {
        if (k < 16) val = wih[k * 192 + 64 + s];
        else if (k < 80) val = whh[(k - 16) * 192 + 64 + s];
      } else if (gate == 2) {
        if (k < 16) val = wih[k * 192 + 128 + s];
      } else {
        if (k >= 16 && k < 80) val = whh[(k - 16) * 192 + 128 + s];
      }
    }
  }
  return val;
}

__global__ __launch_bounds__(256) void k_pack(PackArgs a, short* __restrict__ out, int total) {
  const int g = blockIdx.x * 256 + threadIdx.x;
  if (g < total) out[g] = bf16_(pack_val(a, g));
}

// ---------------------------------------------------------------------------
// var GRU tile (s-remapped): lane owns cols sb=m*4..+3; vector epilogue.
// ---------------------------------------------------------------------------
__device__ __forceinline__ void var_gru_tile(
    const short* wb, const float* gbih, const float* gbhh,
    const short* SA, float* gruH, short* outTile, int outStr,
    int rbase, int Nn, int lane, int wave, int m, int quad, bool writeH)
{
  f32x4 acc[16] = {};
  #pragma unroll
  for (int ks = 0; ks < 3; ++ks) {
    const bf16x8 av = *(const bf16x8*)&SA[(wave * 16 + m) * 104 + ks * 32 + quad * 8];
    #pragma unroll
    for (int nt = 0; nt < 16; ++nt)
      acc[nt] = mfma_16x16x32(av, ((const bf16x8*)(wb + C_G2 * 512))[(nt * 3 + ks) * 64 + lane], acc[nt]);
  }
  const int sb = m * 4;
  const f32x4 bir = *(const f32x4*)(gbih + sb);
  const f32x4 bhr = *(const f32x4*)(gbhh + sb);
  const f32x4 biz = *(const f32x4*)(gbih + 64 + sb);
  const f32x4 bhz = *(const f32x4*)(gbhh + 64 + sb);
  const f32x4 bi4 = *(const f32x4*)(gbih + 128 + sb);
  const f32x4 bh4 = *(const f32x4*)(gbhh + 128 + sb);
  #pragma unroll
  for (int reg = 0; reg < 4; ++reg) {
    const int lr = wave * 16 + quad * 4 + reg, rg = rbase + lr;
    uint2 pv; pv.x = 0u; pv.y = 0u;
    if (rg < Nn) {
      const f32x4 ho = *(const f32x4*)(gruH + (size_t)rg * 64 + sb);
      f32x4 hn;
      #pragma unroll
      for (int nt = 0; nt < 4; ++nt) {
        const float rr = sigmoidf_(acc[nt][reg] + bir[nt] + bhr[nt]);
        const float zz = sigmoidf_(acc[4 + nt][reg] + biz[nt] + bhz[nt]);
        const float nn = tanh_fast(acc[8 + nt][reg] + bi4[nt] + rr * (acc[12 + nt][reg] + bh4[nt]));
        hn[nt] = (1.f - zz) * nn + zz * ho[nt];
      }
      if (writeH) *(f32x4*)(gruH + (size_t)rg * 64 + sb) = hn;
      pv.x = pk2_(hn[0], hn[1]);
      pv.y = pk2_(hn[2], hn[3]);
    }
    *(uint2*)&outTile[lr * outStr + sb] = pv;
  }
}

// ---------------------------------------------------------------------------
// k_phaseA: var GRU (if msgIn) + transposed combined partials -> Abuf/Bbuf.
// (unchanged, 256 threads)
// ---------------------------------------------------------------------------
__global__ __launch_bounds__(256) void k_phaseA(
    const float* __restrict__ msgIn, float* __restrict__ msgZero,
    float* __restrict__ var_h,
    short* __restrict__ Abuf, short* __restrict__ Bbuf,
    const short* __restrict__ wb,
    const float* __restrict__ gbih, const float* __restrict__ gbhh, int N)
{
  __shared__ short SA[64 * 104];
  __shared__ short Xs[64 * 72];
  const int t = threadIdx.x, lane = t & 63, wave = t >> 6;
  const int m = lane & 15, quad = lane >> 4;
  const int rbase = blockIdx.x * 64;

  if (msgIn) {
    {
      const int r = t >> 2, q4 = t & 3, rg = rbase + r;
      #pragma unroll
      for (int i = 0; i < 6; ++i) {
        const int c = q4 * 4 + i * 16;
        f32x4 v = {0.f, 0.f, 0.f, 0.f};
        if (rg < N) {
          if (c < 16)      v = *(const f32x4*)(msgIn + (size_t)rg * 16 + c);
          else if (c < 80) v = *(const f32x4*)(var_h + (size_t)rg * 64 + (c - 16));
        }
        *(unsigned*)&SA[r * 104 + c]     = pk2_(v.x, v.y);
        *(unsigned*)&SA[r * 104 + c + 2] = pk2_(v.z, v.w);
      }
      if (rbase + r < N) {
        f32x4 z = {0.f, 0.f, 0.f, 0.f};
        *(f32x4*)(msgZero + (size_t)(rbase + r) * 16 + q4 * 4) = z;
      }
    }
    __syncthreads();
    var_gru_tile(wb, gbih, gbhh, SA, var_h, Xs, 72,
                 rbase, N, lane, wave, m, quad, true);
    __syncthreads();
  } else {
    const int r = t >> 2, q4 = t & 3, rg = rbase + r;
    #pragma unroll
    for (int i = 0; i < 4; ++i) {
      const int cc = q4 * 4 + i * 16;
      f32x4 v = {0.f, 0.f, 0.f, 0.f};
      if (rg < N) v = *(const f32x4*)(var_h + (size_t)rg * 64 + cc);
      *(unsigned*)&Xs[r * 72 + cc]     = pk2_(v.x, v.y);
      *(unsigned*)&Xs[r * 72 + cc + 2] = pk2_(v.z, v.w);
    }
    __syncthreads();
  }

  f32x4 acc[16] = {};
  #pragma unroll
  for (int ks = 0; ks < 2; ++ks) {
    const bf16x8 bfr = *(const bf16x8*)&Xs[(wave * 16 + m) * 72 + ks * 32 + quad * 8];
    #pragma unroll
    for (int mt = 0; mt < 16; ++mt)
      acc[mt] = mfma_16x16x32(((const bf16x8*)(wb + C_ACOMB * 512))[(mt * 2 + ks) * 64 + lane], bfr, acc[mt]);
  }
  const int rg = rbase + wave * 16 + m;
  if (rg < N) {
    #pragma unroll
    for (int mt = 0; mt < 16; ++mt) {
      const int col = mt * 16 + quad * 4;
      short* dst = (col < 128) ? Abuf : Bbuf;
      uint2 pv;
      pv.x = pk2_(acc[mt][0], acc[mt][1]);
      pv.y = pk2_(acc[mt][2], acc[mt][3]);
      *(uint2*)&dst[(size_t)rg * 128 + (col & 127)] = pv;
    }
  }
}

// ---------------------------------------------------------------------------
// single-wave edge MLP tail (16 edges). NO barriers: single wave, DS in-order.
// ---------------------------------------------------------------------------
__device__ __forceinline__ void edge_tail16(
    const short* wb, int cw2, int cw3,
    const float* b2, const float* b3,
    short* h1s, short* ms, const float* featS,
    int lane, int m, int quad, float* mq)
{
  // L2 transposed: D[col][edge 0..15]; B = h1 rows (all 16)
  {
    f32x4 acc[8] = {};
    #pragma unroll
    for (int ks = 0; ks < 4; ++ks) {
      const bf16x8 bfr = *(const bf16x8*)&h1s[m * 136 + ks * 32 + quad * 8];
      #pragma unroll
      for (int mt = 0; mt < 8; ++mt)
        acc[mt] = mfma_16x16x32(((const bf16x8*)(wb + cw2))[(mt * 4 + ks) * 64 + lane], bfr, acc[mt]);
    }
    #pragma unroll
    for (int mt = 0; mt < 8; ++mt) {
      const int col = mt * 16 + quad * 4;
      const f32x4 bv = *(const f32x4*)(b2 + col);
      uint2 pv;
      pv.x = pk2_(fmaxf(acc[mt][0] + bv[0], 0.f), fmaxf(acc[mt][1] + bv[1], 0.f));
      pv.y = pk2_(fmaxf(acc[mt][2] + bv[2], 0.f), fmaxf(acc[mt][3] + bv[3], 0.f));
      *(uint2*)&h1s[m * 136 + col] = pv;   // h2 (all ds_reads precede, in-order)
    }
  }

  // L3: m-vec = h2 @ W3 ; D[n=j][row=edge]
  f32x4 acc3 = {};
  #pragma unroll
  for (int ks = 0; ks < 4; ++ks) {
    const bf16x8 afr = *(const bf16x8*)&h1s[m * 136 + ks * 32 + quad * 8];
    acc3 = mfma_16x16x32(afr, ((const bf16x8*)(wb + cw3))[ks * 64 + lane], acc3);
  }
  const float b3v = b3[m];
  #pragma unroll
  for (int rr = 0; rr < 4; ++rr) {
    const int row = quad * 4 + rr;           // edge
    ms[row * 40 + m] = pk1_(acc3[rr] + b3v);
    ms[row * 40 + 16 + m] = 0;
  }

  // q transform
  f32x4 accY[5] = {};
  {
    const bf16x8 afr = *(const bf16x8*)&ms[m * 40 + quad * 8];
    #pragma unroll
    for (int tq = 0; tq < 5; ++tq)
      accY[tq] = mfma_16x16x32(afr, ((const bf16x8*)(wb + C_Q * 512))[tq * 64 + lane], accY[tq]);
  }
  #pragma unroll
  for (int rr = 0; rr < 4; ++rr) {
    const int row = quad * 4 + rr;
    const f32x4 f = *(const f32x4*)&featS[row * 4];
    mq[rr] = accY[4][rr] + f.x * accY[0][rr] + f.y * accY[1][rr]
                         + f.z * accY[2][rr] + f.w * accY[3][rr];
  }
}

// ---------------------------------------------------------------------------
// k_phaseB: ONE WAVE per block (64 threads), 16 edges, 8 factors, NO barriers.
// LDS 10.4 KB -> ~15 blocks/CU of independent drifting waves.
// ---------------------------------------------------------------------------
__global__ __launch_bounds__(64) void k_phaseB(
    const short* __restrict__ Abuf, const short* __restrict__ Bbuf,
    const int* __restrict__ v2f_src, const int* __restrict__ f2v_dst,
    const float* __restrict__ featA, const float* __restrict__ featB,
    const float* __restrict__ m1b1, const float* __restrict__ m1b2,
    const float* __restrict__ m1b3,
    const float* __restrict__ m2b1, const float* __restrict__ m2b2,
    const float* __restrict__ m2b3,
    const float* __restrict__ g1bih, const float* __restrict__ g1bhh,
    const short* __restrict__ wb,
    float* __restrict__ fac_h, float* __restrict__ msgV, int E, int F)
{
  __shared__ short h1s[16 * 136];   // 4352 B  (Fs2 16x72 overlays)
  __shared__ short Ps[8 * 136];     // 2176 B  (ms 16x40=640 shorts overlays)
  __shared__ short AsG[16 * 104];   // 3328 B  (rows 8..15 never written: garbage pad)
  __shared__ float fA[64], fB[64];  // 512 B
  short* ms  = Ps;    // 640  <= 1088 shorts
  short* Fs2 = h1s;   // 1152 <= 2176 shorts

  const int t = threadIdx.x;           // one wave
  const int m = t & 15, quad = t >> 4;
  const int e0 = blockIdx.x * 16, f0 = blockIdx.x * 8;
  const int r = t >> 2, q4 = t & 3;    // edge row 0..15, 4 lanes/row

  const bool okR = (e0 + r) < E;
  const int sidx_r = okR ? v2f_src[e0 + r] : 0;
  const int didx_r = okR ? f2v_dst[e0 + r] : 0;
  int aidx[4];
  #pragma unroll
  for (int rr = 0; rr < 4; ++rr) {
    const int er = e0 + quad * 4 + rr;
    aidx[rr] = (er < E) ? f2v_dst[er] : 0;
  }
  fA[t] = ((e0 + (t >> 2)) < E) ? featA[(size_t)e0 * 4 + t] : 0.f;
  fB[t] = ((e0 + (t >> 2)) < E) ? featB[(size_t)e0 * 4 + t] : 0.f;

  // S0: stage fac_h rows f0..f0+7 -> AsG rows 0..7 [pad16|h64|pad16-zero]
  {
    const int hr = t >> 3, hc = (t & 7) * 8;   // hr 0..7
    const int f = f0 + hr;
    f32x4 a0 = {0.f,0.f,0.f,0.f}, a1 = {0.f,0.f,0.f,0.f};
    if (f < F) {
      a0 = *(const f32x4*)(fac_h + (size_t)f * 64 + hc);
      a1 = *(const f32x4*)(fac_h + (size_t)f * 64 + hc + 4);
    }
    uint4 o;
    o.x = pk2_(a0.x, a0.y); o.y = pk2_(a0.z, a0.w);
    o.z = pk2_(a1.x, a1.y); o.w = pk2_(a1.z, a1.w);
    *(uint4*)&AsG[hr * 104 + 16 + hc] = o;
    if (t < 16) {
      uint4 z = make_uint4(0u, 0u, 0u, 0u);
      *(uint4*)&AsG[(t >> 1) * 104 + 80 + (t & 1) * 8] = z;   // zero k-pad rows 0..7
    }
  }

  // S1: v2f dst-partial: Ps[fac 0..7][128] = fac_local @ m1w1_dst (transposed)
  #pragma unroll
  for (int mt = 0; mt < 8; ++mt) {
    f32x4 acc = {};
    #pragma unroll
    for (int ks = 0; ks < 2; ++ks) {
      const bf16x8 bfr = *(const bf16x8*)&AsG[m * 104 + 16 + ks * 32 + quad * 8];
      acc = mfma_16x16x32(((const bf16x8*)(wb + C_W1AD * 512))[(mt * 2 + ks) * 64 + t], bfr, acc);
    }
    if (m < 8) {
      uint2 pv;
      pv.x = pk2_(acc[0], acc[1]);
      pv.y = pk2_(acc[2], acc[3]);
      *(uint2*)&Ps[m * 136 + mt * 16 + quad * 4] = pv;
    }
  }

  // S2: v2f h1 = relu(Abuf[src] + Ps[e>>1] + m1b1)
  {
    const short* pa = Abuf + (size_t)sidx_r * 128;
    const short* pb = Ps + (r >> 1) * 136;
    #pragma unroll
    for (int i = 0; i < 4; ++i) {
      const int col = (q4 + i * 4) * 8;
      uint4 o = make_uint4(0u, 0u, 0u, 0u);
      if (okR) {
        const uint4 ua = *(const uint4*)(pa + col);
        const uint4 ub = *(const uint4*)(pb + col);
        const f32x4 ba = *(const f32x4*)(m1b1 + col);
        const f32x4 bb = *(const f32x4*)(m1b1 + col + 4);
        o.x = pk2_(fmaxf(lo_(ua.x) + lo_(ub.x) + ba.x, 0.f),
                   fmaxf(hi_(ua.x) + hi_(ub.x) + ba.y, 0.f));
        o.y = pk2_(fmaxf(lo_(ua.y) + lo_(ub.y) + ba.z, 0.f),
                   fmaxf(hi_(ua.y) + hi_(ub.y) + ba.w, 0.f));
        o.z = pk2_(fmaxf(lo_(ua.z) + lo_(ub.z) + bb.x, 0.f),
                   fmaxf(hi_(ua.z) + hi_(ub.z) + bb.y, 0.f));
        o.w = pk2_(fmaxf(lo_(ua.w) + lo_(ub.w) + bb.z, 0.f),
                   fmaxf(hi_(ua.w) + hi_(ub.w) + bb.w, 0.f));
      }
      *(uint4*)&h1s[r * 136 + col] = o;
    }
  }

  // edge tail 1
  float mq[4];
  edge_tail16(wb, C_W2A * 512, C_W3A * 512, m1b2, m1b3, h1s, ms, fA, t, m, quad, mq);

  // pair-sum -> AsG msg cols (facs 0..7)
  {
    const int fl = quad * 2;
    AsG[fl * 104 + m]       = pk1_(mq[0] + mq[1]);
    AsG[(fl + 1) * 104 + m] = pk1_(mq[2] + mq[3]);
  }

  // factor GRU on 8 local rows (full-wave gate GEMM, epilogue on quad<2)
  {
    f32x4 acc[16] = {};
    #pragma unroll
    for (int ks = 0; ks < 3; ++ks) {
      const bf16x8 av = *(const bf16x8*)&AsG[m * 104 + ks * 32 + quad * 8];
      #pragma unroll
      for (int nt = 0; nt < 16; ++nt)
        acc[nt] = mfma_16x16x32(av, ((const bf16x8*)(wb + C_G1 * 512))[(nt * 3 + ks) * 64 + t], acc[nt]);
    }
    const int sb = m * 4;
    const f32x4 bir = *(const f32x4*)(g1bih + sb);
    const f32x4 bhr = *(const f32x4*)(g1bhh + sb);
    const f32x4 biz = *(const f32x4*)(g1bih + 64 + sb);
    const f32x4 bhz = *(const f32x4*)(g1bhh + 64 + sb);
    const f32x4 bi4 = *(const f32x4*)(g1bih + 128 + sb);
    const f32x4 bh4 = *(const f32x4*)(g1bhh + 128 + sb);
    if (quad < 2) {
      #pragma unroll
      for (int reg = 0; reg < 4; ++reg) {
        const int lr = quad * 4 + reg;       // local fac 0..7
        const int f = f0 + lr;
        uint2 pv; pv.x = 0u; pv.y = 0u;
        if (f < F) {
          const f32x4 ho = *(const f32x4*)(fac_h + (size_t)f * 64 + sb);
          f32x4 hn;
          #pragma unroll
          for (int nt = 0; nt < 4; ++nt) {
            const float rr = sigmoidf_(acc[nt][reg] + bir[nt] + bhr[nt]);
            const float zz = sigmoidf_(acc[4 + nt][reg] + biz[nt] + bhz[nt]);
            const float nn = tanh_fast(acc[8 + nt][reg] + bi4[nt] + rr * (acc[12 + nt][reg] + bh4[nt]));
            hn[nt] = (1.f - zz) * nn + zz * ho[nt];
          }
          *(f32x4*)(fac_h + (size_t)f * 64 + sb) = hn;
          pv.x = pk2_(hn[0], hn[1]);
          pv.y = pk2_(hn[2], hn[3]);
        }
        *(uint2*)&Fs2[lr * 72 + sb] = pv;
      }
    }
  }

  // f2v src-partial: Ps[fac 0..7][128] = fac_h_new @ m2w1_src
  #pragma unroll
  for (int mt = 0; mt < 8; ++mt) {
    f32x4 acc = {};
    #pragma unroll
    for (int ks = 0; ks < 2; ++ks) {
      const bf16x8 bfr = *(const bf16x8*)&Fs2[m * 72 + ks * 32 + quad * 8];
      acc = mfma_16x16x32(((const bf16x8*)(wb + C_W1BS * 512))[(mt * 2 + ks) * 64 + t], bfr, acc);
    }
    if (m < 8) {
      uint2 pv;
      pv.x = pk2_(acc[0], acc[1]);
      pv.y = pk2_(acc[2], acc[3]);
      *(uint2*)&Ps[m * 136 + mt * 16 + quad * 4] = pv;
    }
  }

  // f2v h1 = relu(Ps[e>>1] + Bbuf[dst] + m2b1)  (overwrites Fs2 region: done)
  {
    const short* pa = Ps + (r >> 1) * 136;
    const short* pb = Bbuf + (size_t)didx_r * 128;
    #pragma unroll
    for (int i = 0; i < 4; ++i) {
      const int col = (q4 + i * 4) * 8;
      uint4 o = make_uint4(0u, 0u, 0u, 0u);
      if (okR) {
        const uint4 ua = *(const uint4*)(pa + col);
        const uint4 ub = *(const uint4*)(pb + col);
        const f32x4 ba = *(const f32x4*)(m2b1 + col);
        const f32x4 bb = *(const f32x4*)(m2b1 + col + 4);
        o.x = pk2_(fmaxf(lo_(ua.x) + lo_(ub.x) + ba.x, 0.f),
                   fmaxf(hi_(ua.x) + hi_(ub.x) + ba.y, 0.f));
        o.y = pk2_(fmaxf(lo_(ua.y) + lo_(ub.y) + ba.z, 0.f),
                   fmaxf(hi_(ua.y) + hi_(ub.y) + ba.w, 0.f));
        o.z = pk2_(fmaxf(lo_(ua.z) + lo_(ub.z) + bb.x, 0.f),
                   fmaxf(hi_(ua.z) + hi_(ub.z) + bb.y, 0.f));
        o.w = pk2_(fmaxf(lo_(ua.w) + lo_(ub.w) + bb.z, 0.f),
                   fmaxf(hi_(ua.w) + hi_(ub.w) + bb.w, 0.f));
      }
      *(uint4*)&h1s[r * 136 + col] = o;
    }
  }

  // edge tail 2 + atomics
  float mq2[4];
  edge_tail16(wb, C_W2B * 512, C_W3B * 512, m2b2, m2b3, h1s, ms, fB, t, m, quad, mq2);
  #pragma unroll
  for (int rr = 0; rr < 4; ++rr) {
    const int erow = quad * 4 + rr;
    if (e0 + erow < E)
      atomicAdd(msgV + (size_t)aidx[rr] * 16 + m, mq2[rr]);
  }
}

// ---------------------------------------------------------------------------
// k_readout_f: final var GRU + RO1 + RO2 (transposed) + RO3 + softmax.
// ---------------------------------------------------------------------------
__global__ __launch_bounds__(256) void k_readout_f(
    const float* __restrict__ gruMsg, const float* __restrict__ gruH,
    const short* __restrict__ wb,
    const float* __restrict__ gbih, const float* __restrict__ gbhh,
    const float* __restrict__ rob1, const float* __restrict__ rob2,
    const float* __restrict__ row3, const float* __restrict__ rob3,
    float* __restrict__ out, int rows)
{
  __shared__ short SA[64 * 104];
  __shared__ short SH[64 * 72];
  __shared__ short S1[64 * 136];
  __shared__ short S2[64 * 136];
  __shared__ float w3s[256];
  const int t = threadIdx.x, lane = t & 63, wave = t >> 6;
  const int m = lane & 15, quad = lane >> 4;
  const int rbase = blockIdx.x * 64;

  w3s[t] = row3[t];
  {
    const int r = t >> 2, q4 = t & 3, rg = rbase + r;
    #pragma unroll
    for (int i = 0; i < 6; ++i) {
      const int c = q4 * 4 + i * 16;
      f32x4 v = {0.f, 0.f, 0.f, 0.f};
      if (rg < rows) {
        if (c < 16)      v = *(const f32x4*)(gruMsg + (size_t)rg * 16 + c);
        else if (c < 80) v = *(const f32x4*)(gruH + (size_t)rg * 64 + (c - 16));
      }
      *(unsigned*)&SA[r * 104 + c]     = pk2_(v.x, v.y);
      *(unsigned*)&SA[r * 104 + c + 2] = pk2_(v.z, v.w);
    }
  }
  __syncthreads();
  var_gru_tile(wb, gbih, gbhh, SA, (float*)gruH, SH, 72,
               rbase, rows, lane, wave, m, quad, false);
  __syncthreads();

  // RO1 (transposed)
  {
    f32x4 acc[8] = {};
    #pragma unroll
    for (int ks = 0; ks < 2; ++ks) {
      const bf16x8 bfr = *(const bf16x8*)&SH[(wave * 16 + m) * 72 + ks * 32 + quad * 8];
      #pragma unroll
      for (int mt = 0; mt < 8; ++mt)
        acc[mt] = mfma_16x16x32(((const bf16x8*)(wb + C_RO1 * 512))[(mt * 2 + ks) * 64 + lane], bfr, acc[mt]);
    }
    #pragma unroll
    for (int mt = 0; mt < 8; ++mt) {
      const int col = mt * 16 + quad * 4;
      const f32x4 bv = *(const f32x4*)(rob1 + col);
      uint2 pv;
      pv.x = pk2_(fmaxf(acc[mt][0] + bv[0], 0.f), fmaxf(acc[mt][1] + bv[1], 0.f));
      pv.y = pk2_(fmaxf(acc[mt][2] + bv[2], 0.f), fmaxf(acc[mt][3] + bv[3], 0.f));
      *(uint2*)&S1[(wave * 16 + m) * 136 + col] = pv;
    }
  }
  __syncthreads();

  // RO2 (transposed)
  {
    f32x4 acc[8] = {};
    #pragma unroll
    for (int ks = 0; ks < 4; ++ks) {
      const bf16x8 bfr = *(const bf16x8*)&S1[(wave * 16 + m) * 136 + ks * 32 + quad * 8];
      #pragma unroll
      for (int mt = 0; mt < 8; ++mt)
        acc[mt] = mfma_16x16x32(((const bf16x8*)(wb + C_RO2 * 512))[(mt * 4 + ks) * 64 + lane], bfr, acc[mt]);
    }
    #pragma unroll
    for (int mt = 0; mt < 8; ++mt) {
      const int col = mt * 16 + quad * 4;
      const f32x4 bv = *(const f32x4*)(rob2 + col);
      uint2 pv;
      pv.x = pk2_(fmaxf(acc[mt][0] + bv[0], 0.f), fmaxf(acc[mt][1] + bv[1], 0.f));
      pv.y = pk2_(fmaxf(acc[mt][2] + bv[2], 0.f), fmaxf(acc[mt][3] + bv[3], 0.f));
      *(uint2*)&S2[(wave * 16 + m) * 136 + col] = pv;
    }
  }
  __syncthreads();

  if (t < 64) {
    const int rg = rbase + t;
    if (rg < rows) {
      float l0 = rob3[0], l1 = rob3[1];
      #pragma unroll 8
      for (int k = 0; k < 128; k += 2) {
        const unsigned u = *(const unsigned*)&S2[t * 136 + k];
        const float x0 = lo_(u), x1 = hi_(u);
        l0 = fmaf(x0, w3s[k * 2 + 0], l0);
        l1 = fmaf(x0, w3s[k * 2 + 1], l1);
        l0 = fmaf(x1, w3s[k * 2 + 2], l0);
        l1 = fmaf(x1, w3s[k * 2 + 3], l1);
      }
      const float mx = fmaxf(l0, l1);
      const float e0 = __expf(l0 - mx), e1 = __expf(l1 - mx);
      const float inv = 1.f / (e0 + e1);
      out[(size_t)rg * 2 + 0] = e0 * inv;
      out[(size_t)rg * 2 + 1] = e1 * inv;
    }
  }
}

// ---------------------------------------------------------------------------
extern "C" void kernel_launch(void* const* d_in, const int* in_sizes, int n_in,
                              void* d_out, int out_size, void* d_ws, size_t ws_size,
                              hipStream_t stream)
{
  const int*   v2f_src  = (const int*)d_in[0];
  const int*   f2v_dst  = (const int*)d_in[3];
  const float* feat_v2f = (const float*)d_in[4];
  const float* feat_f2v = (const float*)d_in[5];
  const float* Qw    = (const float*)d_in[8];
  const float* Qb    = (const float*)d_in[9];
  const float* m1w1  = (const float*)d_in[10];
  const float* m1b1  = (const float*)d_in[11];
  const float* m1w2  = (const float*)d_in[12];
  const float* m1b2  = (const float*)d_in[13];
  const float* m1w3  = (const float*)d_in[14];
  const float* m1b3  = (const float*)d_in[15];
  const float* m2w1  = (const float*)d_in[16];
  const float* m2b1  = (const float*)d_in[17];
  const float* m2w2  = (const float*)d_in[18];
  const float* m2b2  = (const float*)d_in[19];
  const float* m2w3  = (const float*)d_in[20];
  const float* m2b3  = (const float*)d_in[21];
  const float* g1wih = (const float*)d_in[22];
  const float* g1whh = (const float*)d_in[23];
  const float* g1bih = (const float*)d_in[24];
  const float* g1bhh = (const float*)d_in[25];
  const float* g2wih = (const float*)d_in[26];
  const float* g2whh = (const float*)d_in[27];
  const float* g2bih = (const float*)d_in[28];
  const float* g2bhh = (const float*)d_in[29];
  const float* row1  = (const float*)d_in[30];
  const float* rob1  = (const float*)d_in[31];
  const float* row2  = (const float*)d_in[32];
  const float* rob2  = (const float*)d_in[33];
  const float* row3  = (const float*)d_in[34];
  const float* rob3  = (const float*)d_in[35];

  const int E = in_sizes[0];
  const int N = out_size / 2;
  const int F = E / 2;

  float* wsf   = (float*)d_ws;
  float* var_h = wsf;                               // N*64
  float* fac_h = var_h + (size_t)N * 64;            // F*64
  float* msgV  = fac_h + (size_t)F * 64;            // N*16
  short* Abuf  = (short*)(msgV + (size_t)N * 16);   // N*128 bf16
  short* Bbuf  = Abuf + (size_t)N * 128;            // N*128 bf16
  short* wb    = Bbuf + (size_t)N * 128;            // packed weights

  hipMemsetAsync(var_h, 0,
                 ((size_t)N * 64 + (size_t)F * 64 + (size_t)N * 16) * sizeof(float),
                 stream);

  PackArgs pk;
  pk.jb[0] = {m1w2,            128, 4, 32};   // C_W2A
  pk.jb[1] = {m2w2,            128, 4, 32};   // C_W2B
  pk.jb[2] = {m1w3,             16, 4,  4};   // C_W3A
  pk.jb[3] = {m2w3,             16, 4,  4};   // C_W3B
  pk.jb[4] = {m1w1,            128, 2, 16};   // C_ACOMB lo (m1w1 src)
  pk.jb[5] = {m2w1 + 64 * 128, 128, 2, 16};   // C_ACOMB hi (m2w1 dst)
  pk.jb[6] = {m1w1 + 64 * 128, 128, 2, 16};   // C_W1AD
  pk.jb[7] = {m2w1,            128, 2, 16};   // C_W1BS
  pk.jb[8] = {row1,            128, 2, 16};   // C_RO1
  pk.jb[9] = {row2,            128, 4, 32};   // C_RO2
  pk.Qw = Qw; pk.Qb = Qb;
  pk.g1wih = g1wih; pk.g1whh = g1whh;
  pk.g2wih = g2wih; pk.g2whh = g2whh;
  const int packTotal = TOTAL_CHUNKS * 512;
  k_pack<<<(packTotal + 255) / 256, 256, 0, stream>>>(pk, wb, packTotal);

  const int gN   = (N + 63) / 64;
  const int gE16 = (E + 15) / 16;

  for (int step = 0; step < NSTEPS; ++step) {
    k_phaseA<<<gN, 256, 0, stream>>>(
        step ? msgV : nullptr, msgV, var_h, Abuf, Bbuf, wb, g2bih, g2bhh, N);
    k_phaseB<<<gE16, 64, 0, stream>>>(
        Abuf, Bbuf, v2f_src, f2v_dst, feat_v2f, feat_f2v,
        m1b1, m1b2, m1b3, m2b1, m2b2, m2b3, g1bih, g1bhh,
        wb, fac_h, msgV, E, F);
  }

  k_readout_f<<<gN, 256, 0, stream>>>(
      msgV, var_h, wb, g2bih, g2bhh, rob1, rob2, row3, rob3, (float*)d_out, N);
}

// Round 12
// 688.155 us; speedup vs baseline: 1.5079x; 1.2473x over previous
//
#include <hip/hip_runtime.h>

#define NSTEPS 10

typedef __attribute__((ext_vector_type(8))) short bf16x8;
typedef __attribute__((ext_vector_type(4))) float f32x4;

__device__ __forceinline__ float sigmoidf_(float x) { return 1.0f / (1.0f + __expf(-x)); }
__device__ __forceinline__ float tanh_fast(float x) {
  const float e = __expf(2.f * x);
  return 1.f - 2.f / (e + 1.f);
}
__device__ __forceinline__ short bf16_(float x) {   // RNE, pack phase
  union { float f; unsigned u; } c; c.f = x;
  unsigned r = (c.u + 0x7FFFu + ((c.u >> 16) & 1u)) >> 16;
  return (short)r;
}
__device__ __forceinline__ unsigned pk2_(float a, float b) {  // [lo:a|hi:b]
  union { float f; unsigned u; } ca, cb; ca.f = a; cb.f = b;
  return __builtin_amdgcn_perm(cb.u + 0x8000u, ca.u + 0x8000u, 0x07060302u);
}
__device__ __forceinline__ short pk1_(float a) {
  union { float f; unsigned u; } c; c.f = a;
  return (short)((c.u + 0x8000u) >> 16);
}
__device__ __forceinline__ float lo_(unsigned u) { union { unsigned u; float f; } c; c.u = u << 16; return c.f; }
__device__ __forceinline__ float hi_(unsigned u) { union { unsigned u; float f; } c; c.u = u & 0xffff0000u; return c.f; }

__device__ __forceinline__ f32x4 mfma_16x16x32(bf16x8 a, bf16x8 b, f32x4 c) {
  return __builtin_amdgcn_mfma_f32_16x16x32_bf16(a, b, c, 0, 0, 0);
}

// chunk table (1 chunk = 512 bf16)
#define C_W2A   0
#define C_W2B   32
#define C_W3A   64
#define C_W3B   68
#define C_ACOMB 72     // [m1w1 src (16)] + [m2w1 dst (16)]
#define C_W1AD  104
#define C_W1BS  120
#define C_RO1   136
#define C_RO2   152
#define C_Q     184
#define C_G1    189
#define C_G2    237
#define TOTAL_CHUNKS 285

struct PackJob { const float* src; int N; int KS; int nchunks; };
struct PackArgs {
  PackJob jb[10];
  const float* Qw; const float* Qb;
  const float* g1wih; const float* g1whh;
  const float* g2wih; const float* g2whh;
};

__device__ __forceinline__ float pack_val(const PackArgs& a, int g) {
  int c = g >> 9;
  const int r = g & 511;
  const int j = r & 7, n = (r >> 3) & 15, q = (r >> 7) & 3;
  const int kq = q * 8 + j;
  float val = 0.f;
  bool done = false;
  #pragma unroll
  for (int ji = 0; ji < 10; ++ji) {
    if (!done && c < a.jb[ji].nchunks) {
      const int ks = c % a.jb[ji].KS;
      const int nt = c / a.jb[ji].KS;
      const int k = ks * 32 + kq;
      val = a.jb[ji].src[(size_t)k * a.jb[ji].N + nt * 16 + n];
      done = true;
    }
    if (!done) c -= a.jb[ji].nchunks;
  }
  if (!done) {
    if (c < 5) {  // q-transform (K padded 16->32)
      val = 0.f;
      if (kq < 16) val = (c < 4) ? a.Qw[c * 256 + n * 16 + kq] : a.Qb[n * 16 + kq];
    } else {      // GRU: 256 cols = [r|z|in|hn], K=96; s-remap: s = (nq&15)*4 + (nq>>4)
      c -= 5;
      const float* wih = (c < 48) ? a.g1wih : a.g2wih;
      const float* whh = (c < 48) ? a.g1whh : a.g2whh;
      if (c >= 48) c -= 48;
      const int nt = c / 3, ks = c % 3;
      const int k = ks * 32 + kq;
      const int ng = nt * 16 + n;
      const int gate = ng >> 6;
      const int nq = ng & 63;
      const int s = (nq & 15) * 4 + (nq >> 4);
      val = 0.f;
      if (gate == 0) {
        if (k < 16) val = wih[k * 192 + s];
        else if (k < 80) val = whh[(k - 16) * 192 + s];
      } else if (gate == 1) {
        if (k < 16) val = wih[k * 192 + 64 + s];
        else if (k < 80) val = whh[(k - 16) * 192 + 64 + s];
      } else if (gate == 2) {
        if (k < 16) val = wih[k * 192 + 128 + s];
      } else {
        if (k >= 16 && k < 80) val = whh[(k - 16) * 192 + 128 + s];
      }
    }
  }
  return val;
}

__global__ __launch_bounds__(256) void k_pack(PackArgs a, short* __restrict__ out, int total) {
  const int g = blockIdx.x * 256 + threadIdx.x;
  if (g < total) out[g] = bf16_(pack_val(a, g));
}

// ---------------------------------------------------------------------------
// var GRU tile (s-remapped): lane owns cols sb=m*4..+3; vector epilogue.
// ---------------------------------------------------------------------------
__device__ __forceinline__ void var_gru_tile(
    const short* wb, const float* gbih, const float* gbhh,
    const short* SA, float* gruH, short* outTile, int outStr,
    int rbase, int Nn, int lane, int wave, int m, int quad, bool writeH)
{
  f32x4 acc[16] = {};
  #pragma unroll
  for (int ks = 0; ks < 3; ++ks) {
    const bf16x8 av = *(const bf16x8*)&SA[(wave * 16 + m) * 104 + ks * 32 + quad * 8];
    #pragma unroll
    for (int nt = 0; nt < 16; ++nt)
      acc[nt] = mfma_16x16x32(av, ((const bf16x8*)(wb + C_G2 * 512))[(nt * 3 + ks) * 64 + lane], acc[nt]);
  }
  const int sb = m * 4;
  const f32x4 bir = *(const f32x4*)(gbih + sb);
  const f32x4 bhr = *(const f32x4*)(gbhh + sb);
  const f32x4 biz = *(const f32x4*)(gbih + 64 + sb);
  const f32x4 bhz = *(const f32x4*)(gbhh + 64 + sb);
  const f32x4 bi4 = *(const f32x4*)(gbih + 128 + sb);
  const f32x4 bh4 = *(const f32x4*)(gbhh + 128 + sb);
  #pragma unroll
  for (int reg = 0; reg < 4; ++reg) {
    const int lr = wave * 16 + quad * 4 + reg, rg = rbase + lr;
    uint2 pv; pv.x = 0u; pv.y = 0u;
    if (rg < Nn) {
      const f32x4 ho = *(const f32x4*)(gruH + (size_t)rg * 64 + sb);
      f32x4 hn;
      #pragma unroll
      for (int nt = 0; nt < 4; ++nt) {
        const float rr = sigmoidf_(acc[nt][reg] + bir[nt] + bhr[nt]);
        const float zz = sigmoidf_(acc[4 + nt][reg] + biz[nt] + bhz[nt]);
        const float nn = tanh_fast(acc[8 + nt][reg] + bi4[nt] + rr * (acc[12 + nt][reg] + bh4[nt]));
        hn[nt] = (1.f - zz) * nn + zz * ho[nt];
      }
      if (writeH) *(f32x4*)(gruH + (size_t)rg * 64 + sb) = hn;
      pv.x = pk2_(hn[0], hn[1]);
      pv.y = pk2_(hn[2], hn[3]);
    }
    *(uint2*)&outTile[lr * outStr + sb] = pv;
  }
}

// ---------------------------------------------------------------------------
// transposed 128-col partial: Ps[fac 0..31][col 0..127] = src @ W (chunk as A).
// ---------------------------------------------------------------------------
__device__ __forceinline__ void partial_gemm_T(
    const short* chunk, const short* srcTile, int srcStr, short* Ps,
    int lane, int wave, int m, int quad)
{
  const int nt = wave & 1, mt0 = (wave >> 1) * 4;
  f32x4 acc[4] = {};
  #pragma unroll
  for (int ks = 0; ks < 2; ++ks) {
    const bf16x8 bfr = *(const bf16x8*)&srcTile[(nt * 16 + m) * srcStr + ks * 32 + quad * 8];
    #pragma unroll
    for (int j = 0; j < 4; ++j)
      acc[j] = mfma_16x16x32(((const bf16x8*)chunk)[((mt0 + j) * 2 + ks) * 64 + lane], bfr, acc[j]);
  }
  #pragma unroll
  for (int j = 0; j < 4; ++j) {
    const int col = (mt0 + j) * 16 + quad * 4;
    uint2 pv;
    pv.x = pk2_(acc[j][0], acc[j][1]);
    pv.y = pk2_(acc[j][2], acc[j][3]);
    *(uint2*)&Ps[(nt * 16 + m) * 136 + col] = pv;
  }
}

// ---------------------------------------------------------------------------
// edge MLP tail, transposed L2: wave = edge-tile; h2 rows wave-private.
// ---------------------------------------------------------------------------
__device__ __forceinline__ void edge_tail(
    const short* wb, int cw2, int cw3,
    const float* b2, const float* b3,
    short* h1s, short* ms, const float* feats,
    int lane, int wave, int m, int quad, float* mq)
{
  // L2 transposed: D[col][edge]; A = W2 chunk, B = h1 rows (wave-private)
  {
    f32x4 acc[8] = {};
    #pragma unroll
    for (int ks = 0; ks < 4; ++ks) {
      const bf16x8 bfr = *(const bf16x8*)&h1s[(wave * 16 + m) * 136 + ks * 32 + quad * 8];
      #pragma unroll
      for (int mt = 0; mt < 8; ++mt)
        acc[mt] = mfma_16x16x32(((const bf16x8*)(wb + cw2))[(mt * 4 + ks) * 64 + lane], bfr, acc[mt]);
    }
    #pragma unroll
    for (int mt = 0; mt < 8; ++mt) {
      const int col = mt * 16 + quad * 4;
      const f32x4 bv = *(const f32x4*)(b2 + col);
      uint2 pv;
      pv.x = pk2_(fmaxf(acc[mt][0] + bv[0], 0.f), fmaxf(acc[mt][1] + bv[1], 0.f));
      pv.y = pk2_(fmaxf(acc[mt][2] + bv[2], 0.f), fmaxf(acc[mt][3] + bv[3], 0.f));
      *(uint2*)&h1s[(wave * 16 + m) * 136 + col] = pv;
    }
  }
  __syncthreads();   // in-wave cross-lane RAW (h2 cols) + ms-overlay ordering

  // L3: m = h2 @ W3 (wave = edge m-tile)
  f32x4 acc3 = {};
  #pragma unroll
  for (int ks = 0; ks < 4; ++ks) {
    const bf16x8 afr = *(const bf16x8*)&h1s[(wave * 16 + m) * 136 + ks * 32 + quad * 8];
    acc3 = mfma_16x16x32(afr, ((const bf16x8*)(wb + cw3))[ks * 64 + lane], acc3);
  }
  const float b3v = b3[m];
  #pragma unroll
  for (int rr = 0; rr < 4; ++rr) {
    const int row = wave * 16 + quad * 4 + rr;
    ms[row * 40 + m] = pk1_(acc3[rr] + b3v);
    ms[row * 40 + 16 + m] = 0;
  }
  __syncthreads();

  // q transform
  f32x4 accY[5] = {};
  {
    const bf16x8 afr = *(const bf16x8*)&ms[(wave * 16 + m) * 40 + quad * 8];
    #pragma unroll
    for (int tq = 0; tq < 5; ++tq)
      accY[tq] = mfma_16x16x32(afr, ((const bf16x8*)(wb + C_Q * 512))[tq * 64 + lane], accY[tq]);
  }
  #pragma unroll
  for (int rr = 0; rr < 4; ++rr) {
    const int row = wave * 16 + quad * 4 + rr;
    const f32x4 f = *(const f32x4*)&feats[row * 4];
    mq[rr] = accY[4][rr] + f.x * accY[0][rr] + f.y * accY[1][rr]
                         + f.z * accY[2][rr] + f.w * accY[3][rr];
  }
}

// ---------------------------------------------------------------------------
// k_phaseA: var GRU (if msgIn) + transposed combined partials -> Abuf/Bbuf.
// ---------------------------------------------------------------------------
__global__ __launch_bounds__(256) void k_phaseA(
    const float* __restrict__ msgIn, float* __restrict__ msgZero,
    float* __restrict__ var_h,
    short* __restrict__ Abuf, short* __restrict__ Bbuf,
    const short* __restrict__ wb,
    const float* __restrict__ gbih, const float* __restrict__ gbhh, int N)
{
  __shared__ short SA[64 * 104];
  __shared__ short Xs[64 * 72];
  const int t = threadIdx.x, lane = t & 63, wave = t >> 6;
  const int m = lane & 15, quad = lane >> 4;
  const int rbase = blockIdx.x * 64;

  if (msgIn) {
    {
      const int r = t >> 2, q4 = t & 3, rg = rbase + r;
      #pragma unroll
      for (int i = 0; i < 6; ++i) {
        const int c = q4 * 4 + i * 16;
        f32x4 v = {0.f, 0.f, 0.f, 0.f};
        if (rg < N) {
          if (c < 16)      v = *(const f32x4*)(msgIn + (size_t)rg * 16 + c);
          else if (c < 80) v = *(const f32x4*)(var_h + (size_t)rg * 64 + (c - 16));
        }
        *(unsigned*)&SA[r * 104 + c]     = pk2_(v.x, v.y);
        *(unsigned*)&SA[r * 104 + c + 2] = pk2_(v.z, v.w);
      }
      if (rbase + r < N) {
        f32x4 z = {0.f, 0.f, 0.f, 0.f};
        *(f32x4*)(msgZero + (size_t)(rbase + r) * 16 + q4 * 4) = z;
      }
    }
    __syncthreads();
    var_gru_tile(wb, gbih, gbhh, SA, var_h, Xs, 72,
                 rbase, N, lane, wave, m, quad, true);
    __syncthreads();
  } else {
    const int r = t >> 2, q4 = t & 3, rg = rbase + r;
    #pragma unroll
    for (int i = 0; i < 4; ++i) {
      const int cc = q4 * 4 + i * 16;
      f32x4 v = {0.f, 0.f, 0.f, 0.f};
      if (rg < N) v = *(const f32x4*)(var_h + (size_t)rg * 64 + cc);
      *(unsigned*)&Xs[r * 72 + cc]     = pk2_(v.x, v.y);
      *(unsigned*)&Xs[r * 72 + cc + 2] = pk2_(v.z, v.w);
    }
    __syncthreads();
  }

  // transposed combined GEMM: D[col 0..255][row]; wave = row-tile
  f32x4 acc[16] = {};
  #pragma unroll
  for (int ks = 0; ks < 2; ++ks) {
    const bf16x8 bfr = *(const bf16x8*)&Xs[(wave * 16 + m) * 72 + ks * 32 + quad * 8];
    #pragma unroll
    for (int mt = 0; mt < 16; ++mt)
      acc[mt] = mfma_16x16x32(((const bf16x8*)(wb + C_ACOMB * 512))[(mt * 2 + ks) * 64 + lane], bfr, acc[mt]);
  }
  const int rg = rbase + wave * 16 + m;
  if (rg < N) {
    #pragma unroll
    for (int mt = 0; mt < 16; ++mt) {
      const int col = mt * 16 + quad * 4;
      short* dst = (col < 128) ? Abuf : Bbuf;
      uint2 pv;
      pv.x = pk2_(acc[mt][0], acc[mt][1]);
      pv.y = pk2_(acc[mt][2], acc[mt][3]);
      *(uint2*)&dst[(size_t)rg * 128 + (col & 127)] = pv;
    }
  }
}

// ---------------------------------------------------------------------------
// k_phaseB: round-8 structure (best: 60 us/dispatch) + one chain cut:
// pass-2 Bbuf gather prefetched into 16 VGPRs right after pass-1 h1 staging
// (no launch-bounds min -> no spill; occupancy stays LDS-bound 4 blocks/CU).
// ---------------------------------------------------------------------------
__global__ __launch_bounds__(256) void k_phaseB(
    const short* __restrict__ Abuf, const short* __restrict__ Bbuf,
    const int* __restrict__ v2f_src, const int* __restrict__ f2v_dst,
    const float* __restrict__ featA, const float* __restrict__ featB,
    const float* __restrict__ m1b1, const float* __restrict__ m1b2,
    const float* __restrict__ m1b3,
    const float* __restrict__ m2b1, const float* __restrict__ m2b2,
    const float* __restrict__ m2b3,
    const float* __restrict__ g1bih, const float* __restrict__ g1bhh,
    const short* __restrict__ wb,
    float* __restrict__ fac_h, float* __restrict__ msgV, int E, int F)
{
  __shared__ __align__(16) char smemB[38912];
  short* h1s   = (short*)(smemB);            // 64*136 = 17408 B
  short* Ps    = (short*)(smemB + 17408);    // 32*136 = 8704 B (ms overlays)
  short* ms    = (short*)(smemB + 17408);    // 64*40  = 5120 B
  short* AsG   = (short*)(smemB + 26112);    // 32*104 = 6656 B
  short* Fs2   = (short*)(smemB + 32768);    // 32*72  = 4608 B
  float* feats = (float*)(smemB + 37376);    // 64*4   = 1024 B
  int*   sidx  = (int*)(smemB + 38400);      // 256 B
  int*   didx  = (int*)(smemB + 38656);      // 256 B

  const int t = threadIdx.x, lane = t & 63, wave = t >> 6;
  const int m = lane & 15, quad = lane >> 4;
  const int e0 = blockIdx.x * 64, f0 = blockIdx.x * 32;

  if (t < 64) {
    const int eg = e0 + t;
    sidx[t] = (eg < E) ? v2f_src[eg] : 0;
    didx[t] = (eg < E) ? f2v_dst[eg] : 0;
  }
  {
    const int e = t >> 2, k = t & 3, eg = e0 + e;
    feats[e * 4 + k] = (eg < E) ? featA[(size_t)eg * 4 + k] : 0.f;
  }
  {
    const int hr = t >> 3, hc = (t & 7) * 8;
    const int f = f0 + hr;
    f32x4 a0 = {0.f,0.f,0.f,0.f}, a1 = {0.f,0.f,0.f,0.f};
    if (f < F) {
      a0 = *(const f32x4*)(fac_h + (size_t)f * 64 + hc);
      a1 = *(const f32x4*)(fac_h + (size_t)f * 64 + hc + 4);
    }
    uint4 o;
    o.x = pk2_(a0.x, a0.y); o.y = pk2_(a0.z, a0.w);
    o.z = pk2_(a1.x, a1.y); o.w = pk2_(a1.z, a1.w);
    *(uint4*)&AsG[hr * 104 + 16 + hc] = o;
    if (t < 64) {
      uint4 z = make_uint4(0u, 0u, 0u, 0u);
      *(uint4*)&AsG[(t >> 1) * 104 + 80 + (t & 1) * 8] = z;
    }
  }
  __syncthreads();

  // local v2f dst-partial (transposed): Ps = fac_h_local @ m1w1_dst
  partial_gemm_T(wb + C_W1AD * 512, AsG + 16, 104, Ps, lane, wave, m, quad);
  __syncthreads();

  // v2f h1 = relu(Abuf[src] + Ps[e>>1] + m1b1)
  {
    const int r = t >> 2, q4 = t & 3;
    const bool ok = (e0 + r) < E;
    const short* pa = Abuf + (size_t)sidx[r] * 128;
    const short* pb = Ps + (r >> 1) * 136;
    #pragma unroll
    for (int i = 0; i < 4; ++i) {
      const int col = (q4 + i * 4) * 8;
      uint4 o = make_uint4(0u, 0u, 0u, 0u);
      if (ok) {
        const uint4 ua = *(const uint4*)(pa + col);
        const uint4 ub = *(const uint4*)(pb + col);
        const f32x4 ba = *(const f32x4*)(m1b1 + col);
        const f32x4 bb = *(const f32x4*)(m1b1 + col + 4);
        o.x = pk2_(fmaxf(lo_(ua.x) + lo_(ub.x) + ba.x, 0.f),
                   fmaxf(hi_(ua.x) + hi_(ub.x) + ba.y, 0.f));
        o.y = pk2_(fmaxf(lo_(ua.y) + lo_(ub.y) + ba.z, 0.f),
                   fmaxf(hi_(ua.y) + hi_(ub.y) + ba.w, 0.f));
        o.z = pk2_(fmaxf(lo_(ua.z) + lo_(ub.z) + bb.x, 0.f),
                   fmaxf(hi_(ua.z) + hi_(ub.z) + bb.y, 0.f));
        o.w = pk2_(fmaxf(lo_(ua.w) + lo_(ub.w) + bb.z, 0.f),
                   fmaxf(hi_(ua.w) + hi_(ub.w) + bb.w, 0.f));
      }
      *(uint4*)&h1s[r * 136 + col] = o;
    }
  }
  // prefetch pass-2 Bbuf gather (16 VGPRs); latency hides under tail1+GRU+partial2
  uint4 ubP[4];
  {
    const int r = t >> 2, q4 = t & 3;
    const short* pbB = Bbuf + (size_t)didx[r] * 128;
    #pragma unroll
    for (int i = 0; i < 4; ++i)
      ubP[i] = *(const uint4*)(pbB + (q4 + i * 4) * 8);
  }
  __syncthreads();

  float mq[4];
  edge_tail(wb, C_W2A * 512, C_W3A * 512, m1b2, m1b3,
            h1s, ms, feats, lane, wave, m, quad, mq);
  {
    const int fl = wave * 8 + quad * 2;
    AsG[fl * 104 + m]       = pk1_(mq[0] + mq[1]);
    AsG[(fl + 1) * 104 + m] = pk1_(mq[2] + mq[3]);
  }
  __syncthreads();

  // factor GRU on 32 local rows (s-remapped; lane owns 2 consecutive cols)
  {
    const int mtg = wave >> 1, sh = wave & 1;
    f32x4 accG[8] = {};
    #pragma unroll
    for (int ks = 0; ks < 3; ++ks) {
      const bf16x8 av = *(const bf16x8*)&AsG[(mtg * 16 + m) * 104 + ks * 32 + quad * 8];
      #pragma unroll
      for (int g = 0; g < 4; ++g)
        #pragma unroll
        for (int nt2 = 0; nt2 < 2; ++nt2) {
          const int nt = g * 4 + sh * 2 + nt2;
          accG[g * 2 + nt2] = mfma_16x16x32(
              av, ((const bf16x8*)(wb + C_G1 * 512))[(nt * 3 + ks) * 64 + lane],
              accG[g * 2 + nt2]);
        }
    }
    const int sb = m * 4 + sh * 2;
    const float br0 = g1bih[sb] + g1bhh[sb],           br1 = g1bih[sb + 1] + g1bhh[sb + 1];
    const float bz0 = g1bih[64 + sb] + g1bhh[64 + sb], bz1 = g1bih[65 + sb] + g1bhh[65 + sb];
    const float bi0 = g1bih[128 + sb], bi1 = g1bih[129 + sb];
    const float bh0 = g1bhh[128 + sb], bh1 = g1bhh[129 + sb];
    #pragma unroll
    for (int reg = 0; reg < 4; ++reg) {
      const int lr = mtg * 16 + quad * 4 + reg;
      const int f = f0 + lr;
      float hn0 = 0.f, hn1 = 0.f;
      if (f < F) {
        const float2 ho = *(const float2*)(fac_h + (size_t)f * 64 + sb);
        const float r0 = sigmoidf_(accG[0][reg] + br0);
        const float r1 = sigmoidf_(accG[1][reg] + br1);
        const float z0 = sigmoidf_(accG[2][reg] + bz0);
        const float z1 = sigmoidf_(accG[3][reg] + bz1);
        const float n0 = tanh_fast(accG[4][reg] + bi0 + r0 * (accG[6][reg] + bh0));
        const float n1 = tanh_fast(accG[5][reg] + bi1 + r1 * (accG[7][reg] + bh1));
        hn0 = (1.f - z0) * n0 + z0 * ho.x;
        hn1 = (1.f - z1) * n1 + z1 * ho.y;
        float2 hw; hw.x = hn0; hw.y = hn1;
        *(float2*)(fac_h + (size_t)f * 64 + sb) = hw;
      }
      *(unsigned*)&Fs2[lr * 72 + sb] = pk2_(hn0, hn1);
    }
  }
  {
    const int e = t >> 2, k = t & 3, eg = e0 + e;
    feats[e * 4 + k] = (eg < E) ? featB[(size_t)eg * 4 + k] : 0.f;
  }
  __syncthreads();

  // local f2v src-partial (transposed): Ps = fac_h_new @ m2w1_src
  partial_gemm_T(wb + C_W1BS * 512, Fs2, 72, Ps, lane, wave, m, quad);
  __syncthreads();

  // f2v h1 = relu(Ps[e>>1] + ubP + m2b1)
  {
    const int r = t >> 2, q4 = t & 3;
    const bool ok = (e0 + r) < E;
    const short* pa = Ps + (r >> 1) * 136;
    #pragma unroll
    for (int i = 0; i < 4; ++i) {
      const int col = (q4 + i * 4) * 8;
      uint4 o = make_uint4(0u, 0u, 0u, 0u);
      if (ok) {
        const uint4 ua = *(const uint4*)(pa + col);
        const uint4 ub = ubP[i];
        const f32x4 ba = *(const f32x4*)(m2b1 + col);
        const f32x4 bb = *(const f32x4*)(m2b1 + col + 4);
        o.x = pk2_(fmaxf(lo_(ua.x) + lo_(ub.x) + ba.x, 0.f),
                   fmaxf(hi_(ua.x) + hi_(ub.x) + ba.y, 0.f));
        o.y = pk2_(fmaxf(lo_(ua.y) + lo_(ub.y) + ba.z, 0.f),
                   fmaxf(hi_(ua.y) + hi_(ub.y) + ba.w, 0.f));
        o.z = pk2_(fmaxf(lo_(ua.z) + lo_(ub.z) + bb.x, 0.f),
                   fmaxf(hi_(ua.z) + hi_(ub.z) + bb.y, 0.f));
        o.w = pk2_(fmaxf(lo_(ua.w) + lo_(ub.w) + bb.z, 0.f),
                   fmaxf(hi_(ua.w) + hi_(ub.w) + bb.w, 0.f));
      }
      *(uint4*)&h1s[r * 136 + col] = o;
    }
  }
  __syncthreads();

  float mq2[4];
  edge_tail(wb, C_W2B * 512, C_W3B * 512, m2b2, m2b3,
            h1s, ms, feats, lane, wave, m, quad, mq2);
  #pragma unroll
  for (int rr = 0; rr < 4; ++rr) {
    const int erow = wave * 16 + quad * 4 + rr;
    if (e0 + erow < E)
      atomicAdd(msgV + (size_t)didx[erow] * 16 + m, mq2[rr]);
  }
}

// ---------------------------------------------------------------------------
// k_readout_f: final var GRU + RO1 + RO2 (transposed) + RO3 + softmax.
// ---------------------------------------------------------------------------
__global__ __launch_bounds__(256) void k_readout_f(
    const float* __restrict__ gruMsg, const float* __restrict__ gruH,
    const short* __restrict__ wb,
    const float* __restrict__ gbih, const float* __restrict__ gbhh,
    const float* __restrict__ rob1, const float* __restrict__ rob2,
    const float* __restrict__ row3, const float* __restrict__ rob3,
    float* __restrict__ out, int rows)
{
  __shared__ short SA[64 * 104];
  __shared__ short SH[64 * 72];
  __shared__ short S1[64 * 136];
  __shared__ short S2[64 * 136];
  __shared__ float w3s[256];
  const int t = threadIdx.x, lane = t & 63, wave = t >> 6;
  const int m = lane & 15, quad = lane >> 4;
  const int rbase = blockIdx.x * 64;

  w3s[t] = row3[t];
  {
    const int r = t >> 2, q4 = t & 3, rg = rbase + r;
    #pragma unroll
    for (int i = 0; i < 6; ++i) {
      const int c = q4 * 4 + i * 16;
      f32x4 v = {0.f, 0.f, 0.f, 0.f};
      if (rg < rows) {
        if (c < 16)      v = *(const f32x4*)(gruMsg + (size_t)rg * 16 + c);
        else if (c < 80) v = *(const f32x4*)(gruH + (size_t)rg * 64 + (c - 16));
      }
      *(unsigned*)&SA[r * 104 + c]     = pk2_(v.x, v.y);
      *(unsigned*)&SA[r * 104 + c + 2] = pk2_(v.z, v.w);
    }
  }
  __syncthreads();
  var_gru_tile(wb, gbih, gbhh, SA, (float*)gruH, SH, 72,
               rbase, rows, lane, wave, m, quad, false);
  __syncthreads();

  // RO1 (transposed)
  {
    f32x4 acc[8] = {};
    #pragma unroll
    for (int ks = 0; ks < 2; ++ks) {
      const bf16x8 bfr = *(const bf16x8*)&SH[(wave * 16 + m) * 72 + ks * 32 + quad * 8];
      #pragma unroll
      for (int mt = 0; mt < 8; ++mt)
        acc[mt] = mfma_16x16x32(((const bf16x8*)(wb + C_RO1 * 512))[(mt * 2 + ks) * 64 + lane], bfr, acc[mt]);
    }
    #pragma unroll
    for (int mt = 0; mt < 8; ++mt) {
      const int col = mt * 16 + quad * 4;
      const f32x4 bv = *(const f32x4*)(rob1 + col);
      uint2 pv;
      pv.x = pk2_(fmaxf(acc[mt][0] + bv[0], 0.f), fmaxf(acc[mt][1] + bv[1], 0.f));
      pv.y = pk2_(fmaxf(acc[mt][2] + bv[2], 0.f), fmaxf(acc[mt][3] + bv[3], 0.f));
      *(uint2*)&S1[(wave * 16 + m) * 136 + col] = pv;
    }
  }
  __syncthreads();

  // RO2 (transposed)
  {
    f32x4 acc[8] = {};
    #pragma unroll
    for (int ks = 0; ks < 4; ++ks) {
      const bf16x8 bfr = *(const bf16x8*)&S1[(wave * 16 + m) * 136 + ks * 32 + quad * 8];
      #pragma unroll
      for (int mt = 0; mt < 8; ++mt)
        acc[mt] = mfma_16x16x32(((const bf16x8*)(wb + C_RO2 * 512))[(mt * 4 + ks) * 64 + lane], bfr, acc[mt]);
    }
    #pragma unroll
    for (int mt = 0; mt < 8; ++mt) {
      const int col = mt * 16 + quad * 4;
      const f32x4 bv = *(const f32x4*)(rob2 + col);
      uint2 pv;
      pv.x = pk2_(fmaxf(acc[mt][0] + bv[0], 0.f), fmaxf(acc[mt][1] + bv[1], 0.f));
      pv.y = pk2_(fmaxf(acc[mt][2] + bv[2], 0.f), fmaxf(acc[mt][3] + bv[3], 0.f));
      *(uint2*)&S2[(wave * 16 + m) * 136 + col] = pv;
    }
  }
  __syncthreads();

  if (t < 64) {
    const int rg = rbase + t;
    if (rg < rows) {
      float l0 = rob3[0], l1 = rob3[1];
      #pragma unroll 8
      for (int k = 0; k < 128; k += 2) {
        const unsigned u = *(const unsigned*)&S2[t * 136 + k];
        const float x0 = lo_(u), x1 = hi_(u);
        l0 = fmaf(x0, w3s[k * 2 + 0], l0);
        l1 = fmaf(x0, w3s[k * 2 + 1], l1);
        l0 = fmaf(x1, w3s[k * 2 + 2], l0);
        l1 = fmaf(x1, w3s[k * 2 + 3], l1);
      }
      const float mx = fmaxf(l0, l1);
      const float e0 = __expf(l0 - mx), e1 = __expf(l1 - mx);
      const float inv = 1.f / (e0 + e1);
      out[(size_t)rg * 2 + 0] = e0 * inv;
      out[(size_t)rg * 2 + 1] = e1 * inv;
    }
  }
}

// ---------------------------------------------------------------------------
extern "C" void kernel_launch(void* const* d_in, const int* in_sizes, int n_in,
                              void* d_out, int out_size, void* d_ws, size_t ws_size,
                              hipStream_t stream)
{
  const int*   v2f_src  = (const int*)d_in[0];
  const int*   f2v_dst  = (const int*)d_in[3];
  const float* feat_v2f = (const float*)d_in[4];
  const float* feat_f2v = (const float*)d_in[5];
  const float* Qw    = (const float*)d_in[8];
  const float* Qb    = (const float*)d_in[9];
  const float* m1w1  = (const float*)d_in[10];
  const float* m1b1  = (const float*)d_in[11];
  const float* m1w2  = (const float*)d_in[12];
  const float* m1b2  = (const float*)d_in[13];
  const float* m1w3  = (const float*)d_in[14];
  const float* m1b3  = (const float*)d_in[15];
  const float* m2w1  = (const float*)d_in[16];
  const float* m2b1  = (const float*)d_in[17];
  const float* m2w2  = (const float*)d_in[18];
  const float* m2b2  = (const float*)d_in[19];
  const float* m2w3  = (const float*)d_in[20];
  const float* m2b3  = (const float*)d_in[21];
  const float* g1wih = (const float*)d_in[22];
  const float* g1whh = (const float*)d_in[23];
  const float* g1bih = (const float*)d_in[24];
  const float* g1bhh = (const float*)d_in[25];
  const float* g2wih = (const float*)d_in[26];
  const float* g2whh = (const float*)d_in[27];
  const float* g2bih = (const float*)d_in[28];
  const float* g2bhh = (const float*)d_in[29];
  const float* row1  = (const float*)d_in[30];
  const float* rob1  = (const float*)d_in[31];
  const float* row2  = (const float*)d_in[32];
  const float* rob2  = (const float*)d_in[33];
  const float* row3  = (const float*)d_in[34];
  const float* rob3  = (const float*)d_in[35];

  const int E = in_sizes[0];
  const int N = out_size / 2;
  const int F = E / 2;

  float* wsf   = (float*)d_ws;
  float* var_h = wsf;                               // N*64
  float* fac_h = var_h + (size_t)N * 64;            // F*64
  float* msgV  = fac_h + (size_t)F * 64;            // N*16
  short* Abuf  = (short*)(msgV + (size_t)N * 16);   // N*128 bf16
  short* Bbuf  = Abuf + (size_t)N * 128;            // N*128 bf16
  short* wb    = Bbuf + (size_t)N * 128;            // packed weights

  hipMemsetAsync(var_h, 0,
                 ((size_t)N * 64 + (size_t)F * 64 + (size_t)N * 16) * sizeof(float),
                 stream);

  PackArgs pk;
  pk.jb[0] = {m1w2,            128, 4, 32};   // C_W2A
  pk.jb[1] = {m2w2,            128, 4, 32};   // C_W2B
  pk.jb[2] = {m1w3,             16, 4,  4};   // C_W3A
  pk.jb[3] = {m2w3,             16, 4,  4};   // C_W3B
  pk.jb[4] = {m1w1,            128, 2, 16};   // C_ACOMB lo (m1w1 src)
  pk.jb[5] = {m2w1 + 64 * 128, 128, 2, 16};   // C_ACOMB hi (m2w1 dst)
  pk.jb[6] = {m1w1 + 64 * 128, 128, 2, 16};   // C_W1AD
  pk.jb[7] = {m2w1,            128, 2, 16};   // C_W1BS
  pk.jb[8] = {row1,            128, 2, 16};   // C_RO1
  pk.jb[9] = {row2,            128, 4, 32};   // C_RO2
  pk.Qw = Qw; pk.Qb = Qb;
  pk.g1wih = g1wih; pk.g1whh = g1whh;
  pk.g2wih = g2wih; pk.g2whh = g2whh;
  const int packTotal = TOTAL_CHUNKS * 512;
  k_pack<<<(packTotal + 255) / 256, 256, 0, stream>>>(pk, wb, packTotal);

  const int gN = (N + 63) / 64;
  const int gE = (E + 63) / 64;

  for (int step = 0; step < NSTEPS; ++step) {
    k_phaseA<<<gN, 256, 0, stream>>>(
        step ? msgV : nullptr, msgV, var_h, Abuf, Bbuf, wb, g2bih, g2bhh, N);
    k_phaseB<<<gE, 256, 0, stream>>>(
        Abuf, Bbuf, v2f_src, f2v_dst, feat_v2f, feat_f2v,
        m1b1, m1b2, m1b3, m2b1, m2b2, m2b3, g1bih, g1bhh,
        wb, fac_h, msgV, E, F);
  }

  k_readout_f<<<gN, 256, 0, stream>>>(
      msgV, var_h, wb, g2bih, g2bhh, rob1, rob2, row3, rob3, (float*)d_out, N);
}